// Round 3
// baseline (45071.469 us; speedup 1.0000x reference)
//
#include <hip/hip_runtime.h>
#include <hip/hip_cooperative_groups.h>
#include <cstdint>
#include <cstddef>

#define TT 128
#define BB 64
#define EE 256
#define HH 1024
#define VV 8000
#define LSTRIDE 132   // LDS row stride: 16B-aligned, 4i-bank starts (optimal b128)

// ---------------- threefry2x32 (20 rounds), bit-exact vs JAX partitionable ----------------
__device__ __forceinline__ uint32_t rotl32(uint32_t v, int r){ return (v<<r)|(v>>(32-r)); }

__device__ __forceinline__ void tf2x32(uint32_t k0, uint32_t k1, uint32_t x0, uint32_t x1,
                                       uint32_t& y0, uint32_t& y1)
{
  const uint32_t k2 = k0 ^ k1 ^ 0x1BD11BDAu;
  x0 += k0; x1 += k1;
#define TFR(r) { x0 += x1; x1 = rotl32(x1,(r)); x1 ^= x0; }
  TFR(13) TFR(15) TFR(26) TFR(6)   x0 += k1; x1 += k2 + 1u;
  TFR(17) TFR(29) TFR(16) TFR(24)  x0 += k2; x1 += k0 + 2u;
  TFR(13) TFR(15) TFR(26) TFR(6)   x0 += k0; x1 += k1 + 3u;
  TFR(17) TFR(29) TFR(16) TFR(24)  x0 += k1; x1 += k2 + 4u;
  TFR(13) TFR(15) TFR(26) TFR(6)   x0 += k2; x1 += k0 + 5u;
#undef TFR
  y0 = x0; y1 = x1;
}

// uniform in [tiny,1): bit-exact fp32 recipe of jax uniform(minval=tiny, maxval=1)
__device__ __forceinline__ float u01f(uint32_t bits){
  float f = __uint_as_float((bits >> 9) | 0x3f800000u) - 1.0f;
  return (f == 0.0f) ? 1.17549435e-38f : f;
}

// ---------------- XLA EmitFastTanh, non-FMA form (mul/add separate roundings) ------------
__device__ __forceinline__ float xla_tanh(float x){
  float xc = fminf(fmaxf(x, -7.90531110763549805f), 7.90531110763549805f);
  float x2 = __fmul_rn(xc, xc);
  float num = -2.76076847742355e-16f;
  num = __fadd_rn(__fmul_rn(x2, num),  2.00018790482477e-13f);
  num = __fadd_rn(__fmul_rn(x2, num), -8.60467152213735e-11f);
  num = __fadd_rn(__fmul_rn(x2, num),  5.12229709037114e-08f);
  num = __fadd_rn(__fmul_rn(x2, num),  1.48572235717979e-05f);
  num = __fadd_rn(__fmul_rn(x2, num),  6.37261928875436e-04f);
  num = __fadd_rn(__fmul_rn(x2, num),  4.89352455891786e-03f);
  num = __fmul_rn(xc, num);
  float den = 1.19825839466702e-06f;
  den = __fadd_rn(__fmul_rn(x2, den), 1.18534705686654e-04f);
  den = __fadd_rn(__fmul_rn(x2, den), 2.26843463243900e-03f);
  den = __fadd_rn(__fmul_rn(x2, den), 4.89352518554385e-03f);
  float r = __fdiv_rn(num, den);
  return (fabsf(x) < 0.0004f) ? x : r;
}

// XLA LogisticExpander: logistic(x) = 0.5 + 0.5*tanh(0.5*x), separate roundings
__device__ __forceinline__ float xla_sigmoid(float x){
  float t = xla_tanh(__fmul_rn(0.5f, x));
  return __fadd_rn(0.5f, __fmul_rn(0.5f, t));
}

// pack fp32 score + v; ties -> smaller v (first-max, matching jnp.argmax)
__device__ __forceinline__ unsigned long long pack32(float s, int v){
  uint32_t u = __float_as_uint(s);
  u = (u >> 31) ? ~u : (u | 0x80000000u);
  return ((unsigned long long)u << 32) | (unsigned)(8191 - v);
}

// agent-scope (cross-XCD coherent) relaxed scalar load
__device__ __forceinline__ float agld(const float* p){
  return __hip_atomic_load(p, __ATOMIC_RELAXED, __HIP_MEMORY_SCOPE_AGENT);
}

// ---------------- init ----------------
__global__ void initz(float* ring, unsigned long long* best, int* flags){
  int i = blockIdx.x*256 + threadIdx.x;
  if (i < 2*HH*BB) ring[i] = 0.f;
  if (i < TT*BB)   best[i] = 0ull;
  if (i < 256)     flags[i] = 0;
}

// ---------------- px precompute: px[t][e][b] = emb[x[b][t]][e] ----------------
__global__ __launch_bounds__(256) void pxgen(
    const int* __restrict__ x, const float* __restrict__ emb, float* __restrict__ px)
{
  int flat = blockIdx.x*256 + threadIdx.x;      // 128*256*64 = 2M
  int b = flat & 63;
  int e = (flat >> 6) & 255;
  int t = flat >> 14;
  if (t >= TT) return;
  int tok = x[b*TT + t];
  px[((size_t)t*EE + e)*BB + b] = emb[(size_t)tok*EE + e];
}

// ---------------- transpose 4 gate matrices: in [R][C] -> out[(g*C + c)*R + r] ----------------
__global__ __launch_bounds__(256) void transpose4f(
    const float* __restrict__ g0, const float* __restrict__ g1,
    const float* __restrict__ g2, const float* __restrict__ g3,
    float* __restrict__ out, int R, int C)
{
  const float* in = (blockIdx.y==0)?g0:(blockIdx.y==1)?g1:(blockIdx.y==2)?g2:g3;
  int tilesC = C >> 6;
  int tr = blockIdx.x / tilesC, tc = blockIdx.x % tilesC;
  __shared__ float tile[64][65];
  int tid = threadIdx.x;
  #pragma unroll
  for (int s = 0; s < 16; ++s) {
    int li = s*256 + tid;
    int r = li >> 6, c = li & 63;
    tile[r][c] = in[(size_t)(tr*64 + r)*C + tc*64 + c];
  }
  __syncthreads();
  #pragma unroll
  for (int s = 0; s < 16; ++s) {
    int li = s*256 + tid;
    int c = li >> 6, r = li & 63;
    out[((size_t)blockIdx.y*C + tc*64 + c)*R + tr*64 + r] = tile[r][c];
  }
}

// chunk-slice load: 16 coalesced 4B agent loads into 4 named float4s (REGISTERS --
// never an address-taken array: R1's float P[16] via lambda pointer went to scratch.
// Explicit names, NO token pasting (Q##0.x lexes "0.x" as one pp-number -> invalid).
#define LOADC(QA, QB, QC, QD, hp, hcn) {                                      \
  const float* _s = (hp) + (size_t)((hcn)*128 + kb)*BB + lane;                \
  QA.x=agld(_s+ 0*BB); QA.y=agld(_s+ 1*BB); QA.z=agld(_s+ 2*BB); QA.w=agld(_s+ 3*BB); \
  QB.x=agld(_s+ 4*BB); QB.y=agld(_s+ 5*BB); QB.z=agld(_s+ 6*BB); QB.w=agld(_s+ 7*BB); \
  QC.x=agld(_s+ 8*BB); QC.y=agld(_s+ 9*BB); QC.z=agld(_s+10*BB); QC.w=agld(_s+11*BB); \
  QD.x=agld(_s+12*BB); QD.y=agld(_s+13*BB); QD.z=agld(_s+14*BB); QD.w=agld(_s+15*BB); }

// plain (non-atomic) variant for px loads
#define LOADP(QA, QB, QC, QD, src) {                                          \
  const float* _s = (src);                                                    \
  QA.x=_s[ 0*BB]; QA.y=_s[ 1*BB]; QA.z=_s[ 2*BB]; QA.w=_s[ 3*BB];            \
  QB.x=_s[ 4*BB]; QB.y=_s[ 5*BB]; QB.z=_s[ 6*BB]; QB.w=_s[ 7*BB];            \
  QC.x=_s[ 8*BB]; QC.y=_s[ 9*BB]; QC.z=_s[10*BB]; QC.w=_s[11*BB];            \
  QD.x=_s[12*BB]; QD.y=_s[13*BB]; QD.z=_s[14*BB]; QD.w=_s[15*BB]; }

// conflict-free staging store: 4x ds_write_b128 at lane*132 + kb (+0/16/32/48B);
// 8-lane groups land on distinct bank-quads -> 0-way conflict
#define STOREC(QA, QB, QC, QD, buf) {                                         \
  float* _d = (buf) + lane*LSTRIDE + kb;                                      \
  *(float4*)(_d+ 0)=QA; *(float4*)(_d+ 4)=QB;                                 \
  *(float4*)(_d+ 8)=QC; *(float4*)(_d+12)=QD; }

#define LGKM0 asm volatile("s_waitcnt lgkmcnt(0)" ::: "memory")

// ---------------- cooperative LSTM recurrence: XLA-CPU faithful, fast transport -----------
// 256 blocks x 512 threads (8 waves). Wave w: p = w>>1 -> jc = bid*4+p; half = w&1 ->
// gates {i,f} (half0) or {og,c} (half1). Lanes = batch b. Each gate's mul/add chain is
// computed end-to-end by one thread => exact reference rounding (xw chain e=0..255;
// hU panels folded at k=288/576/864).
//
// R3 = R1 structure (raw s_barrier + lgkmcnt-only waits in hot loop; vmcnt never
// drained so h-chunk prefetch stays in flight across barriers; depth-2 prefetch;
// 1 barrier/chunk; conflict-free b128 staging; hist off the drain path) with the
// prefetch state in NAMED float4 registers via explicit-name macros (no arrays ->
// no scratch; no token pasting -> compiles).
__global__ __launch_bounds__(512, 2) void lstm_rec(
    const float* __restrict__ Wt, const float* __restrict__ Ut,
    const float* __restrict__ bi, const float* __restrict__ bf,
    const float* __restrict__ bog, const float* __restrict__ bc,
    const float* __restrict__ px, float* __restrict__ ring,
    float* __restrict__ hist, int* __restrict__ flags)
{
  __shared__ float sA[64*LSTRIDE];
  __shared__ float sB[64*LSTRIDE];
  __shared__ float spx[64*LSTRIDE];
  __shared__ float xch[512];

  const int tid  = threadIdx.x;
  const int w    = tid >> 6;
  const int lane = tid & 63;
  const int p    = w >> 1;
  const int half = w & 1;
  const int ju   = __builtin_amdgcn_readfirstlane(blockIdx.x*4 + p);
  const int g0   = 2*half, g1 = 2*half + 1;
  const int kb   = w*16;            // this wave's 16-row k slice within a 128-chunk

  const float* U0 = Ut + ((size_t)g0*HH + ju)*HH;
  const float* U1 = Ut + ((size_t)g1*HH + ju)*HH;
  const float* W0 = Wt + ((size_t)g0*HH + ju)*EE;
  const float* W1 = Wt + ((size_t)g1*HH + ju)*EE;
  const float biaA = half ? bog[ju] : bi[ju];
  const float biaB = half ? bc[ju]  : bf[ju];

  float c = 0.f;
  float B0 = 0.f, B1 = 0.f;       // xw+bias for my 2 gates
  float R0 = 0.f, R1 = 0.f, T0 = 0.f, T1 = 0.f;
  float4 pA0, pA1, pA2, pA3;      // depth-2 prefetch state, registers only
  float4 pB0, pB1, pB2, pB3;

  // exact-rounding MAC chain over one 128-k chunk (Eigen kc=288 panel folds)
  auto chunkMAC = [&](const float* cur, int hc){
    #pragma unroll
    for (int sub = 0; sub < 4; ++sub) {
      int kabs = hc*128 + sub*32;
      if (kabs == 288 || kabs == 576 || kabs == 864) {   // Eigen C += panel (CR add)
        T0 = __fadd_rn(T0, R0); R0 = 0.f;
        T1 = __fadd_rn(T1, R1); R1 = 0.f;
      }
      #pragma unroll
      for (int q = sub*32; q < sub*32 + 32; q += 4) {
        float4 h4 = *(const float4*)&cur[lane*LSTRIDE + q];
        R0 = __fadd_rn(R0, __fmul_rn(h4.x, U0[hc*128 + q + 0]));
        R1 = __fadd_rn(R1, __fmul_rn(h4.x, U1[hc*128 + q + 0]));
        R0 = __fadd_rn(R0, __fmul_rn(h4.y, U0[hc*128 + q + 1]));
        R1 = __fadd_rn(R1, __fmul_rn(h4.y, U1[hc*128 + q + 1]));
        R0 = __fadd_rn(R0, __fmul_rn(h4.z, U0[hc*128 + q + 2]));
        R1 = __fadd_rn(R1, __fmul_rn(h4.z, U1[hc*128 + q + 2]));
        R0 = __fadd_rn(R0, __fmul_rn(h4.w, U0[hc*128 + q + 3]));
        R1 = __fadd_rn(R1, __fmul_rn(h4.w, U1[hc*128 + q + 3]));
      }
    }
  };

  // xw chains for my 2 gates at step t2 (exact e=0..255 mul/add order, then +bias)
  auto compute_xw = [&](int t2){
    float A0 = 0.f, A1 = 0.f;
    const float* pxt = px + (size_t)t2*EE*BB + (size_t)kb*BB + lane;
    float4 pX0, pX1, pX2, pX3;    // named float4 regs, no arrays
    float4 pY0, pY1, pY2, pY3;
    LOADP(pX0, pX1, pX2, pX3, pxt);
    LOADP(pY0, pY1, pY2, pY3, pxt + (size_t)128*BB);
    STOREC(pX0, pX1, pX2, pX3, spx);
    LGKM0;
    __builtin_amdgcn_s_barrier();
    #pragma unroll
    for (int e = 0; e < 128; e += 4) {
      float4 p4 = *(const float4*)&spx[lane*LSTRIDE + e];
      A0 = __fadd_rn(A0, __fmul_rn(p4.x, W0[e + 0]));
      A1 = __fadd_rn(A1, __fmul_rn(p4.x, W1[e + 0]));
      A0 = __fadd_rn(A0, __fmul_rn(p4.y, W0[e + 1]));
      A1 = __fadd_rn(A1, __fmul_rn(p4.y, W1[e + 1]));
      A0 = __fadd_rn(A0, __fmul_rn(p4.z, W0[e + 2]));
      A1 = __fadd_rn(A1, __fmul_rn(p4.z, W1[e + 2]));
      A0 = __fadd_rn(A0, __fmul_rn(p4.w, W0[e + 3]));
      A1 = __fadd_rn(A1, __fmul_rn(p4.w, W1[e + 3]));
    }
    LGKM0;                                // all reads of spx retired before restage
    __builtin_amdgcn_s_barrier();
    STOREC(pY0, pY1, pY2, pY3, spx);
    LGKM0;
    __builtin_amdgcn_s_barrier();
    #pragma unroll
    for (int e = 0; e < 128; e += 4) {
      float4 p4 = *(const float4*)&spx[lane*LSTRIDE + e];
      A0 = __fadd_rn(A0, __fmul_rn(p4.x, W0[128 + e + 0]));
      A1 = __fadd_rn(A1, __fmul_rn(p4.x, W1[128 + e + 0]));
      A0 = __fadd_rn(A0, __fmul_rn(p4.y, W0[128 + e + 1]));
      A1 = __fadd_rn(A1, __fmul_rn(p4.y, W1[128 + e + 1]));
      A0 = __fadd_rn(A0, __fmul_rn(p4.z, W0[128 + e + 2]));
      A1 = __fadd_rn(A1, __fmul_rn(p4.z, W1[128 + e + 2]));
      A0 = __fadd_rn(A0, __fmul_rn(p4.w, W0[128 + e + 3]));
      A1 = __fadd_rn(A1, __fmul_rn(p4.w, W1[128 + e + 3]));
    }
    B0 = __fadd_rn(A0, biaA);
    B1 = __fadd_rn(A1, biaB);
  };

  compute_xw(0);   // prologue: xw for t=0

  #pragma unroll 1
  for (int t = 0; t < TT; ++t) {
    const float* hp = ring + (size_t)(t & 1)*(HH*BB);
    float*       rn = ring + (size_t)((t+1) & 1)*(HH*BB);

    // ---- h @ U: depth-2 prefetch, 1 raw barrier per chunk, vmcnt never drained ----
    LOADC(pA0, pA1, pA2, pA3, hp, 0);
    LOADC(pB0, pB1, pB2, pB3, hp, 1);
    R0 = 0.f; R1 = 0.f; T0 = 0.f; T1 = 0.f;
    #pragma unroll 1
    for (int hc = 0; hc < 8; hc += 2) {
      STOREC(pA0, pA1, pA2, pA3, sA);      // waits pA loads via reg deps (counted vmcnt)
      if (hc < 6) LOADC(pA0, pA1, pA2, pA3, hp, hc + 2);  // prefetch in flight across barrier
      LGKM0;
      __builtin_amdgcn_s_barrier();
      chunkMAC(sA, hc);
      STOREC(pB0, pB1, pB2, pB3, sB);
      if (hc < 6) LOADC(pB0, pB1, pB2, pB3, hp, hc + 3);
      LGKM0;
      __builtin_amdgcn_s_barrier();
      chunkMAC(sB, hc + 1);
    }
    T0 = __fadd_rn(T0, R0);                 // final panel fold
    T1 = __fadd_rn(T1, R1);
    float z0 = __fadd_rn(B0, T0);           // z = fl(xw + hU)
    float z1 = __fadd_rn(B1, T1);

    // ---- gates: half1 computes tanh(zc), sig(zo); half0 computes sig(zi), sig(zf) ----
    float igv = 0.f, fgv = 0.f, hv = 0.f;
    if (half) {
      float th  = xla_tanh(z1);
      float ogs = xla_sigmoid(z0);
      xch[p*64 + lane]       = th;
      xch[256 + p*64 + lane] = ogs;
    } else {
      igv = xla_sigmoid(z0);
      fgv = xla_sigmoid(z1);
    }
    LGKM0;
    __builtin_amdgcn_s_barrier();           // xch visible (LDS only -> no vmcnt drain)
    if (!half) {
      float th  = xch[p*64 + lane];
      float ogs = xch[256 + p*64 + lane];
      c = __fadd_rn(__fmul_rn(fgv, c), __fmul_rn(igv, th));
      hv = __fmul_rn(ogs, xla_tanh(c));
      __hip_atomic_store(&rn[(size_t)ju*BB + lane], hv,
                         __ATOMIC_RELAXED, __HIP_MEMORY_SCOPE_AGENT);
    }
    __syncthreads();   // REQUIRED vmcnt(0) drain: all waves' h stores done before flag
    if (tid == 0)
      __hip_atomic_store(&flags[blockIdx.x], t+1, __ATOMIC_RELEASE, __HIP_MEMORY_SCOPE_AGENT);
    if (!half && t >= 64)                   // hist off the drain path; consumed post-kernel
      hist[(size_t)(t-64)*(HH*BB) + (size_t)ju*BB + lane] = hv;

    if (t < TT-1) {
      compute_xw(t+1);    // overlapped with other blocks finishing step t
      if (w == 0) {       // wave0 polls all 256 flags (4 per lane)
        for (;;) {
          int m0 = __hip_atomic_load(&flags[lane],       __ATOMIC_RELAXED, __HIP_MEMORY_SCOPE_AGENT);
          int m1 = __hip_atomic_load(&flags[64 + lane],  __ATOMIC_RELAXED, __HIP_MEMORY_SCOPE_AGENT);
          int m2 = __hip_atomic_load(&flags[128 + lane], __ATOMIC_RELAXED, __HIP_MEMORY_SCOPE_AGENT);
          int m3 = __hip_atomic_load(&flags[192 + lane], __ATOMIC_RELAXED, __HIP_MEMORY_SCOPE_AGENT);
          int mm = m0 < m1 ? m0 : m1;
          int nn = m2 < m3 ? m2 : m3;
          mm = mm < nn ? mm : nn;
          if (__all(mm >= t+1)) break;
          __builtin_amdgcn_s_sleep(1);
        }
        __atomic_signal_fence(__ATOMIC_ACQUIRE);
      }
      __syncthreads();    // release everyone into step t+1 (drains stray hist stores too)
    }
  }
}

// ---------------- logits + gumbel argmax: XLA-CPU faithful (unchanged, verified) ----------
__global__ __launch_bounds__(256, 2) void logits_samp(
    const float* __restrict__ hist, const float* __restrict__ Wo,
    const float* __restrict__ bo, const int* __restrict__ gnp,
    unsigned long long* __restrict__ best)
{
  const int t = 64 + blockIdx.y;
  if (t < gnp[0]) return;
  const int vt   = blockIdx.x;     // [0,8)
  const int z    = blockIdx.z;     // [0,4) b-quarter
  const int tid  = threadIdx.x;
  const int w    = tid >> 6;
  const int lane = tid & 63;

  int v[4], vc[4]; bool val[4];
  #pragma unroll
  for (int vj = 0; vj < 4; ++vj) {
    v[vj]  = vt*1024 + vj*256 + tid;
    val[vj] = (v[vj] < VV);
    vc[vj] = val[vj] ? v[vj] : (VV-1);
  }

  __shared__ float hds[128*16];
  __shared__ unsigned long long red[4][16];

  float tot[64], reg[64];
  #pragma unroll
  for (int i = 0; i < 64; ++i) { tot[i] = 0.f; reg[i] = 0.f; }

  const float* hf = hist + (size_t)(t-64)*(HH*BB);

  #pragma unroll 1
  for (int kc8 = 0; kc8 < 8; ++kc8) {
    __syncthreads();
    #pragma unroll
    for (int s = 0; s < 8; ++s) {
      int idx = s*256 + tid;
      int kl = idx >> 4, bb = idx & 15;
      hds[idx] = hf[(size_t)(kc8*128 + kl)*BB + z*16 + bb];
    }
    __syncthreads();
    #pragma unroll 1
    for (int sub = 0; sub < 4; ++sub) {
      int kabs = kc8*128 + sub*32;
      if (kabs == 288 || kabs == 576 || kabs == 864) {
        #pragma unroll
        for (int i = 0; i < 64; ++i) { tot[i] = __fadd_rn(tot[i], reg[i]); reg[i] = 0.f; }
      }
      #pragma unroll 2
      for (int k = sub*32; k < sub*32 + 32; ++k) {
        const float* wr = Wo + (size_t)(kc8*128 + k)*VV;
        float wv0 = wr[vc[0]], wv1 = wr[vc[1]], wv2 = wr[vc[2]], wv3 = wr[vc[3]];
        #pragma unroll
        for (int bb = 0; bb < 16; ++bb) {
          float hb = hds[k*16 + bb];
          reg[0*16+bb] = __fadd_rn(reg[0*16+bb], __fmul_rn(hb, wv0));
          reg[1*16+bb] = __fadd_rn(reg[1*16+bb], __fmul_rn(hb, wv1));
          reg[2*16+bb] = __fadd_rn(reg[2*16+bb], __fmul_rn(hb, wv2));
          reg[3*16+bb] = __fadd_rn(reg[3*16+bb], __fmul_rn(hb, wv3));
        }
      }
    }
  }
  #pragma unroll
  for (int i = 0; i < 64; ++i) tot[i] = __fadd_rn(tot[i], reg[i]);

  uint32_t kt0, kt1;
  tf2x32(0u, 1u, 0u, (uint32_t)t, kt0, kt1);
  float bov[4];
  #pragma unroll
  for (int vj = 0; vj < 4; ++vj) bov[vj] = val[vj] ? bo[v[vj]] : 0.f;

  #pragma unroll 1
  for (int bb = 0; bb < 16; ++bb) {
    int bglob = z*16 + bb;
    unsigned long long pm = 0ull;
    #pragma unroll
    for (int vj = 0; vj < 4; ++vj) {
      if (val[vj]) {
        uint32_t y0, y1;
        tf2x32(kt0, kt1, 0u, (uint32_t)(bglob*VV + v[vj]), y0, y1);
        float u  = u01f(y0 ^ y1);
        float l1 = logf(u);
        float l2 = logf(-l1);
        float g  = -l2;
        float L  = __fadd_rn(tot[vj*16 + bb], bov[vj]);
        float sc = __fadd_rn(g, L);
        unsigned long long pk = pack32(sc, v[vj]);
        if (pk > pm) pm = pk;
      }
    }
    #pragma unroll
    for (int m = 32; m > 0; m >>= 1) {
      unsigned long long q = __shfl_xor(pm, m);
      if (q > pm) pm = q;
    }
    if (lane == 0) red[w][bb] = pm;
    __syncthreads();
    if (tid == 0) {
      unsigned long long m0 = red[0][bb];
      if (red[1][bb] > m0) m0 = red[1][bb];
      if (red[2][bb] > m0) m0 = red[2][bb];
      if (red[3][bb] > m0) m0 = red[3][bb];
      atomicMax(&best[(size_t)t*BB + z*16 + bb], m0);
    }
    __syncthreads();
  }
}

// ---------------- finalize ----------------
__global__ void finalize(const int* __restrict__ x, const int* __restrict__ gnp,
                         const unsigned long long* __restrict__ best, int* __restrict__ out)
{
  int i = blockIdx.x*256 + threadIdx.x;
  if (i >= BB*TT) return;
  int t = i & 127;
  int b = i >> 7;
  if (t < gnp[0] || t < 64) out[i] = x[i];
  else out[i] = 8191 - (int)(best[(size_t)t*BB + b] & 0x1FFFull);
}

// ---------------- launch ----------------
extern "C" void kernel_launch(void* const* d_in, const int* in_sizes, int n_in,
                              void* d_out, int out_size, void* d_ws, size_t ws_size,
                              hipStream_t stream)
{
  const int*   x    = (const int*)  d_in[0];
  const int*   gn   = (const int*)  d_in[1];
  const float* emb  = (const float*)d_in[2];
  const float* Wi   = (const float*)d_in[3];
  const float* Ui   = (const float*)d_in[4];
  const float* bi   = (const float*)d_in[5];
  const float* Wf   = (const float*)d_in[6];
  const float* Uf   = (const float*)d_in[7];
  const float* bf   = (const float*)d_in[8];
  const float* Wog  = (const float*)d_in[9];
  const float* Uog  = (const float*)d_in[10];
  const float* bog  = (const float*)d_in[11];
  const float* Wc   = (const float*)d_in[12];
  const float* Uc   = (const float*)d_in[13];
  const float* bc   = (const float*)d_in[14];
  const float* Wo   = (const float*)d_in[15];
  const float* bo   = (const float*)d_in[16];

  // ws: Ut 16MB | Wt 4MB | ring 512KB | hist 16MB | px 8MB | best 64KB | flags 1KB
  float* Ut   = (float*)d_ws;                              // 4Mi floats
  float* Wt   = Ut + (size_t)4*1024*1024;                  // 1Mi floats
  float* ring = Wt + (size_t)1024*1024;                    // 2*65536 floats
  float* hist = ring + (size_t)2*HH*BB;                    // 64*65536 floats
  float* px   = hist + (size_t)64*HH*BB;                   // 128*256*64 floats
  unsigned long long* best =
      (unsigned long long*)(px + (size_t)TT*EE*BB);        // 8192 u64
  int* flags  = (int*)(best + (size_t)TT*BB);              // 256 int

  initz<<<512, 256, 0, stream>>>(ring, best, flags);
  transpose4f<<<dim3(256,4), 256, 0, stream>>>(Ui, Uf, Uog, Uc, Ut, 1024, 1024);
  transpose4f<<<dim3(64,4),  256, 0, stream>>>(Wi, Wf, Wog, Wc, Wt, 256, 1024);
  pxgen<<<8192, 256, 0, stream>>>(x, emb, px);

  const float* Wtp = Wt; const float* Utp = Ut;
  const float* bip = bi; const float* bfp = bf; const float* bogp = bog; const float* bcp = bc;
  const float* pxp = px; float* ringp = ring; float* histp = hist; int* flagsp = flags;
  void* kargs[] = { (void*)&Wtp, (void*)&Utp,
                    (void*)&bip, (void*)&bfp, (void*)&bogp, (void*)&bcp,
                    (void*)&pxp, (void*)&ringp, (void*)&histp, (void*)&flagsp };
  hipLaunchCooperativeKernel((void*)lstm_rec, dim3(256), dim3(512), kargs, 0, stream);

  logits_samp<<<dim3(8,64,4), 256, 0, stream>>>(hist, Wo, bo, gn, best);
  finalize<<<32, 256, 0, stream>>>(x, gn, best, (int*)d_out);
}

// Round 4
// 45053.339 us; speedup vs baseline: 1.0004x; 1.0004x over previous
//
#include <hip/hip_runtime.h>
#include <hip/hip_cooperative_groups.h>
#include <cstdint>
#include <cstddef>

#define TT 128
#define BB 64
#define EE 256
#define HH 1024
#define VV 8000
#define LSTRIDE 132   // LDS row stride: 16B-aligned, 4i-bank starts (optimal b128)

// ---------------- threefry2x32 (20 rounds), bit-exact vs JAX partitionable ----------------
__device__ __forceinline__ uint32_t rotl32(uint32_t v, int r){ return (v<<r)|(v>>(32-r)); }

__device__ __forceinline__ void tf2x32(uint32_t k0, uint32_t k1, uint32_t x0, uint32_t x1,
                                       uint32_t& y0, uint32_t& y1)
{
  const uint32_t k2 = k0 ^ k1 ^ 0x1BD11BDAu;
  x0 += k0; x1 += k1;
#define TFR(r) { x0 += x1; x1 = rotl32(x1,(r)); x1 ^= x0; }
  TFR(13) TFR(15) TFR(26) TFR(6)   x0 += k1; x1 += k2 + 1u;
  TFR(17) TFR(29) TFR(16) TFR(24)  x0 += k2; x1 += k0 + 2u;
  TFR(13) TFR(15) TFR(26) TFR(6)   x0 += k0; x1 += k1 + 3u;
  TFR(17) TFR(29) TFR(16) TFR(24)  x0 += k1; x1 += k2 + 4u;
  TFR(13) TFR(15) TFR(26) TFR(6)   x0 += k2; x1 += k0 + 5u;
#undef TFR
  y0 = x0; y1 = x1;
}

// uniform in [tiny,1): bit-exact fp32 recipe of jax uniform(minval=tiny, maxval=1)
__device__ __forceinline__ float u01f(uint32_t bits){
  float f = __uint_as_float((bits >> 9) | 0x3f800000u) - 1.0f;
  return (f == 0.0f) ? 1.17549435e-38f : f;
}

// ---------------- XLA EmitFastTanh, non-FMA form (mul/add separate roundings) ------------
__device__ __forceinline__ float xla_tanh(float x){
  float xc = fminf(fmaxf(x, -7.90531110763549805f), 7.90531110763549805f);
  float x2 = __fmul_rn(xc, xc);
  float num = -2.76076847742355e-16f;
  num = __fadd_rn(__fmul_rn(x2, num),  2.00018790482477e-13f);
  num = __fadd_rn(__fmul_rn(x2, num), -8.60467152213735e-11f);
  num = __fadd_rn(__fmul_rn(x2, num),  5.12229709037114e-08f);
  num = __fadd_rn(__fmul_rn(x2, num),  1.48572235717979e-05f);
  num = __fadd_rn(__fmul_rn(x2, num),  6.37261928875436e-04f);
  num = __fadd_rn(__fmul_rn(x2, num),  4.89352455891786e-03f);
  num = __fmul_rn(xc, num);
  float den = 1.19825839466702e-06f;
  den = __fadd_rn(__fmul_rn(x2, den), 1.18534705686654e-04f);
  den = __fadd_rn(__fmul_rn(x2, den), 2.26843463243900e-03f);
  den = __fadd_rn(__fmul_rn(x2, den), 4.89352518554385e-03f);
  float r = __fdiv_rn(num, den);
  return (fabsf(x) < 0.0004f) ? x : r;
}

// XLA LogisticExpander: logistic(x) = 0.5 + 0.5*tanh(0.5*x), separate roundings
__device__ __forceinline__ float xla_sigmoid(float x){
  float t = xla_tanh(__fmul_rn(0.5f, x));
  return __fadd_rn(0.5f, __fmul_rn(0.5f, t));
}

// pack fp32 score + v; ties -> smaller v (first-max, matching jnp.argmax)
__device__ __forceinline__ unsigned long long pack32(float s, int v){
  uint32_t u = __float_as_uint(s);
  u = (u >> 31) ? ~u : (u | 0x80000000u);
  return ((unsigned long long)u << 32) | (unsigned)(8191 - v);
}

// agent-scope (cross-XCD coherent) relaxed scalar load
__device__ __forceinline__ float agld(const float* p){
  return __hip_atomic_load(p, __ATOMIC_RELAXED, __HIP_MEMORY_SCOPE_AGENT);
}

// ---------------- init ----------------
__global__ void initz(float* ring, unsigned long long* best, int* flags){
  int i = blockIdx.x*256 + threadIdx.x;
  if (i < 2*HH*BB) ring[i] = 0.f;
  if (i < TT*BB)   best[i] = 0ull;
  if (i < 256)     flags[i] = 0;
}

// ---------------- px precompute: px[t][e][b] = emb[x[b][t]][e] ----------------
__global__ __launch_bounds__(256) void pxgen(
    const int* __restrict__ x, const float* __restrict__ emb, float* __restrict__ px)
{
  int flat = blockIdx.x*256 + threadIdx.x;      // 128*256*64 = 2M
  int b = flat & 63;
  int e = (flat >> 6) & 255;
  int t = flat >> 14;
  if (t >= TT) return;
  int tok = x[b*TT + t];
  px[((size_t)t*EE + e)*BB + b] = emb[(size_t)tok*EE + e];
}

// ---------------- transpose 4 gate matrices: in [R][C] -> out[(g*C + c)*R + r] ----------------
__global__ __launch_bounds__(256) void transpose4f(
    const float* __restrict__ g0, const float* __restrict__ g1,
    const float* __restrict__ g2, const float* __restrict__ g3,
    float* __restrict__ out, int R, int C)
{
  const float* in = (blockIdx.y==0)?g0:(blockIdx.y==1)?g1:(blockIdx.y==2)?g2:g3;
  int tilesC = C >> 6;
  int tr = blockIdx.x / tilesC, tc = blockIdx.x % tilesC;
  __shared__ float tile[64][65];
  int tid = threadIdx.x;
  #pragma unroll
  for (int s = 0; s < 16; ++s) {
    int li = s*256 + tid;
    int r = li >> 6, c = li & 63;
    tile[r][c] = in[(size_t)(tr*64 + r)*C + tc*64 + c];
  }
  __syncthreads();
  #pragma unroll
  for (int s = 0; s < 16; ++s) {
    int li = s*256 + tid;
    int c = li >> 6, r = li & 63;
    out[((size_t)blockIdx.y*C + tc*64 + c)*R + tr*64 + r] = tile[r][c];
  }
}

// chunk-slice load: 16 coalesced 4B agent loads into 4 named float4s (registers;
// explicit names, no token pasting, no address-taken arrays)
#define LOADC(QA, QB, QC, QD, hp, hcn) {                                      \
  const float* _s = (hp) + (size_t)((hcn)*128 + kb)*BB + lane;                \
  QA.x=agld(_s+ 0*BB); QA.y=agld(_s+ 1*BB); QA.z=agld(_s+ 2*BB); QA.w=agld(_s+ 3*BB); \
  QB.x=agld(_s+ 4*BB); QB.y=agld(_s+ 5*BB); QB.z=agld(_s+ 6*BB); QB.w=agld(_s+ 7*BB); \
  QC.x=agld(_s+ 8*BB); QC.y=agld(_s+ 9*BB); QC.z=agld(_s+10*BB); QC.w=agld(_s+11*BB); \
  QD.x=agld(_s+12*BB); QD.y=agld(_s+13*BB); QD.z=agld(_s+14*BB); QD.w=agld(_s+15*BB); }

// plain (non-atomic) variant for px loads
#define LOADP(QA, QB, QC, QD, src) {                                          \
  const float* _s = (src);                                                    \
  QA.x=_s[ 0*BB]; QA.y=_s[ 1*BB]; QA.z=_s[ 2*BB]; QA.w=_s[ 3*BB];            \
  QB.x=_s[ 4*BB]; QB.y=_s[ 5*BB]; QB.z=_s[ 6*BB]; QB.w=_s[ 7*BB];            \
  QC.x=_s[ 8*BB]; QC.y=_s[ 9*BB]; QC.z=_s[10*BB]; QC.w=_s[11*BB];            \
  QD.x=_s[12*BB]; QD.y=_s[13*BB]; QD.z=_s[14*BB]; QD.w=_s[15*BB]; }

// conflict-free staging store: 4x ds_write_b128 at lane*132 + kb (+0/16/32/48B);
// 8-lane groups land on distinct bank-quads -> 0-way conflict
#define STOREC(QA, QB, QC, QD, buf) {                                         \
  float* _d = (buf) + lane*LSTRIDE + kb;                                      \
  *(float4*)(_d+ 0)=QA; *(float4*)(_d+ 4)=QB;                                 \
  *(float4*)(_d+ 8)=QC; *(float4*)(_d+12)=QD; }

#define LGKM0 asm volatile("s_waitcnt lgkmcnt(0)" ::: "memory")

// ---------------- cooperative LSTM recurrence: XLA-CPU faithful, fast transport -----------
// 256 blocks x 512 threads (8 waves). Wave w: p = w>>1 -> jc = bid*4+p; half = w&1 ->
// gates {i,f} (half0) or {og,c} (half1). Lanes = batch b. Each gate's mul/add chain is
// computed end-to-end by one thread => exact reference rounding (xw chain e=0..255;
// hU panels folded at k=288/576/864).
//
// R4: __launch_bounds__(512) (no min-waves arg). The prior (512,2) capped the
// allocator at 128 VGPRs; the 32-float h-prefetch + 32-float xw state live across
// fully-unrolled MAC loops then spilled to scratch -> deterministic ~82GB writes +
// ~45GB fetches per dispatch (R1/R3 signature). Grid is 256 blocks on 256 CUs
// (cooperative), so runtime occupancy is 1 block/CU either way; cap 256 costs
// nothing. Also: pY px-loads issued after MAC loop 1 (halves xw live state).
__global__ __launch_bounds__(512) void lstm_rec(
    const float* __restrict__ Wt, const float* __restrict__ Ut,
    const float* __restrict__ bi, const float* __restrict__ bf,
    const float* __restrict__ bog, const float* __restrict__ bc,
    const float* __restrict__ px, float* __restrict__ ring,
    float* __restrict__ hist, int* __restrict__ flags)
{
  __shared__ float sA[64*LSTRIDE];
  __shared__ float sB[64*LSTRIDE];
  __shared__ float spx[64*LSTRIDE];
  __shared__ float xch[512];

  const int tid  = threadIdx.x;
  const int w    = tid >> 6;
  const int lane = tid & 63;
  const int p    = w >> 1;
  const int half = w & 1;
  const int ju   = __builtin_amdgcn_readfirstlane(blockIdx.x*4 + p);
  const int g0   = 2*half, g1 = 2*half + 1;
  const int kb   = w*16;            // this wave's 16-row k slice within a 128-chunk

  const float* U0 = Ut + ((size_t)g0*HH + ju)*HH;
  const float* U1 = Ut + ((size_t)g1*HH + ju)*HH;
  const float* W0 = Wt + ((size_t)g0*HH + ju)*EE;
  const float* W1 = Wt + ((size_t)g1*HH + ju)*EE;
  const float biaA = half ? bog[ju] : bi[ju];
  const float biaB = half ? bc[ju]  : bf[ju];

  float c = 0.f;
  float B0 = 0.f, B1 = 0.f;       // xw+bias for my 2 gates
  float R0 = 0.f, R1 = 0.f, T0 = 0.f, T1 = 0.f;
  float4 pA0, pA1, pA2, pA3;      // depth-2 prefetch state, registers only
  float4 pB0, pB1, pB2, pB3;

  // exact-rounding MAC chain over one 128-k chunk (Eigen kc=288 panel folds)
  auto chunkMAC = [&](const float* cur, int hc){
    #pragma unroll
    for (int sub = 0; sub < 4; ++sub) {
      int kabs = hc*128 + sub*32;
      if (kabs == 288 || kabs == 576 || kabs == 864) {   // Eigen C += panel (CR add)
        T0 = __fadd_rn(T0, R0); R0 = 0.f;
        T1 = __fadd_rn(T1, R1); R1 = 0.f;
      }
      #pragma unroll
      for (int q = sub*32; q < sub*32 + 32; q += 4) {
        float4 h4 = *(const float4*)&cur[lane*LSTRIDE + q];
        R0 = __fadd_rn(R0, __fmul_rn(h4.x, U0[hc*128 + q + 0]));
        R1 = __fadd_rn(R1, __fmul_rn(h4.x, U1[hc*128 + q + 0]));
        R0 = __fadd_rn(R0, __fmul_rn(h4.y, U0[hc*128 + q + 1]));
        R1 = __fadd_rn(R1, __fmul_rn(h4.y, U1[hc*128 + q + 1]));
        R0 = __fadd_rn(R0, __fmul_rn(h4.z, U0[hc*128 + q + 2]));
        R1 = __fadd_rn(R1, __fmul_rn(h4.z, U1[hc*128 + q + 2]));
        R0 = __fadd_rn(R0, __fmul_rn(h4.w, U0[hc*128 + q + 3]));
        R1 = __fadd_rn(R1, __fmul_rn(h4.w, U1[hc*128 + q + 3]));
      }
    }
  };

  // xw chains for my 2 gates at step t2 (exact e=0..255 mul/add order, then +bias)
  auto compute_xw = [&](int t2){
    float A0 = 0.f, A1 = 0.f;
    const float* pxt = px + (size_t)t2*EE*BB + (size_t)kb*BB + lane;
    float4 pX0, pX1, pX2, pX3;    // named float4 regs, no arrays
    LOADP(pX0, pX1, pX2, pX3, pxt);
    STOREC(pX0, pX1, pX2, pX3, spx);
    LGKM0;
    __builtin_amdgcn_s_barrier();
    #pragma unroll
    for (int e = 0; e < 128; e += 4) {
      float4 p4 = *(const float4*)&spx[lane*LSTRIDE + e];
      A0 = __fadd_rn(A0, __fmul_rn(p4.x, W0[e + 0]));
      A1 = __fadd_rn(A1, __fmul_rn(p4.x, W1[e + 0]));
      A0 = __fadd_rn(A0, __fmul_rn(p4.y, W0[e + 1]));
      A1 = __fadd_rn(A1, __fmul_rn(p4.y, W1[e + 1]));
      A0 = __fadd_rn(A0, __fmul_rn(p4.z, W0[e + 2]));
      A1 = __fadd_rn(A1, __fmul_rn(p4.z, W1[e + 2]));
      A0 = __fadd_rn(A0, __fmul_rn(p4.w, W0[e + 3]));
      A1 = __fadd_rn(A1, __fmul_rn(p4.w, W1[e + 3]));
    }
    // second-half px loads issued here (not up front): halves live xw state;
    // loads stay in flight across the barrier (vmcnt not drained)
    float4 pY0, pY1, pY2, pY3;
    LOADP(pY0, pY1, pY2, pY3, pxt + (size_t)128*BB);
    LGKM0;                                // all reads of spx retired before restage
    __builtin_amdgcn_s_barrier();
    STOREC(pY0, pY1, pY2, pY3, spx);
    LGKM0;
    __builtin_amdgcn_s_barrier();
    #pragma unroll
    for (int e = 0; e < 128; e += 4) {
      float4 p4 = *(const float4*)&spx[lane*LSTRIDE + e];
      A0 = __fadd_rn(A0, __fmul_rn(p4.x, W0[128 + e + 0]));
      A1 = __fadd_rn(A1, __fmul_rn(p4.x, W1[128 + e + 0]));
      A0 = __fadd_rn(A0, __fmul_rn(p4.y, W0[128 + e + 1]));
      A1 = __fadd_rn(A1, __fmul_rn(p4.y, W1[128 + e + 1]));
      A0 = __fadd_rn(A0, __fmul_rn(p4.z, W0[128 + e + 2]));
      A1 = __fadd_rn(A1, __fmul_rn(p4.z, W1[128 + e + 2]));
      A0 = __fadd_rn(A0, __fmul_rn(p4.w, W0[128 + e + 3]));
      A1 = __fadd_rn(A1, __fmul_rn(p4.w, W1[128 + e + 3]));
    }
    B0 = __fadd_rn(A0, biaA);
    B1 = __fadd_rn(A1, biaB);
  };

  compute_xw(0);   // prologue: xw for t=0

  #pragma unroll 1
  for (int t = 0; t < TT; ++t) {
    const float* hp = ring + (size_t)(t & 1)*(HH*BB);
    float*       rn = ring + (size_t)((t+1) & 1)*(HH*BB);

    // ---- h @ U: depth-2 prefetch, 1 raw barrier per chunk, vmcnt never drained ----
    LOADC(pA0, pA1, pA2, pA3, hp, 0);
    LOADC(pB0, pB1, pB2, pB3, hp, 1);
    R0 = 0.f; R1 = 0.f; T0 = 0.f; T1 = 0.f;
    #pragma unroll 1
    for (int hc = 0; hc < 8; hc += 2) {
      STOREC(pA0, pA1, pA2, pA3, sA);      // waits pA loads via reg deps (counted vmcnt)
      if (hc < 6) LOADC(pA0, pA1, pA2, pA3, hp, hc + 2);  // prefetch in flight across barrier
      LGKM0;
      __builtin_amdgcn_s_barrier();
      chunkMAC(sA, hc);
      STOREC(pB0, pB1, pB2, pB3, sB);
      if (hc < 6) LOADC(pB0, pB1, pB2, pB3, hp, hc + 3);
      LGKM0;
      __builtin_amdgcn_s_barrier();
      chunkMAC(sB, hc + 1);
    }
    T0 = __fadd_rn(T0, R0);                 // final panel fold
    T1 = __fadd_rn(T1, R1);
    float z0 = __fadd_rn(B0, T0);           // z = fl(xw + hU)
    float z1 = __fadd_rn(B1, T1);

    // ---- gates: half1 computes tanh(zc), sig(zo); half0 computes sig(zi), sig(zf) ----
    float igv = 0.f, fgv = 0.f, hv = 0.f;
    if (half) {
      float th  = xla_tanh(z1);
      float ogs = xla_sigmoid(z0);
      xch[p*64 + lane]       = th;
      xch[256 + p*64 + lane] = ogs;
    } else {
      igv = xla_sigmoid(z0);
      fgv = xla_sigmoid(z1);
    }
    LGKM0;
    __builtin_amdgcn_s_barrier();           // xch visible (LDS only -> no vmcnt drain)
    if (!half) {
      float th  = xch[p*64 + lane];
      float ogs = xch[256 + p*64 + lane];
      c = __fadd_rn(__fmul_rn(fgv, c), __fmul_rn(igv, th));
      hv = __fmul_rn(ogs, xla_tanh(c));
      __hip_atomic_store(&rn[(size_t)ju*BB + lane], hv,
                         __ATOMIC_RELAXED, __HIP_MEMORY_SCOPE_AGENT);
    }
    __syncthreads();   // REQUIRED vmcnt(0) drain: all waves' h stores done before flag
    if (tid == 0)
      __hip_atomic_store(&flags[blockIdx.x], t+1, __ATOMIC_RELEASE, __HIP_MEMORY_SCOPE_AGENT);
    if (!half && t >= 64)                   // hist off the drain path; consumed post-kernel
      hist[(size_t)(t-64)*(HH*BB) + (size_t)ju*BB + lane] = hv;

    if (t < TT-1) {
      compute_xw(t+1);    // overlapped with other blocks finishing step t
      if (w == 0) {       // wave0 polls all 256 flags (4 per lane)
        for (;;) {
          int m0 = __hip_atomic_load(&flags[lane],       __ATOMIC_RELAXED, __HIP_MEMORY_SCOPE_AGENT);
          int m1 = __hip_atomic_load(&flags[64 + lane],  __ATOMIC_RELAXED, __HIP_MEMORY_SCOPE_AGENT);
          int m2 = __hip_atomic_load(&flags[128 + lane], __ATOMIC_RELAXED, __HIP_MEMORY_SCOPE_AGENT);
          int m3 = __hip_atomic_load(&flags[192 + lane], __ATOMIC_RELAXED, __HIP_MEMORY_SCOPE_AGENT);
          int mm = m0 < m1 ? m0 : m1;
          int nn = m2 < m3 ? m2 : m3;
          mm = mm < nn ? mm : nn;
          if (__all(mm >= t+1)) break;
          __builtin_amdgcn_s_sleep(1);
        }
        __atomic_signal_fence(__ATOMIC_ACQUIRE);
      }
      __syncthreads();    // release everyone into step t+1 (drains stray hist stores too)
    }
  }
}

// ---------------- logits + gumbel argmax: XLA-CPU faithful (unchanged, verified) ----------
__global__ __launch_bounds__(256, 2) void logits_samp(
    const float* __restrict__ hist, const float* __restrict__ Wo,
    const float* __restrict__ bo, const int* __restrict__ gnp,
    unsigned long long* __restrict__ best)
{
  const int t = 64 + blockIdx.y;
  if (t < gnp[0]) return;
  const int vt   = blockIdx.x;     // [0,8)
  const int z    = blockIdx.z;     // [0,4) b-quarter
  const int tid  = threadIdx.x;
  const int w    = tid >> 6;
  const int lane = tid & 63;

  int v[4], vc[4]; bool val[4];
  #pragma unroll
  for (int vj = 0; vj < 4; ++vj) {
    v[vj]  = vt*1024 + vj*256 + tid;
    val[vj] = (v[vj] < VV);
    vc[vj] = val[vj] ? v[vj] : (VV-1);
  }

  __shared__ float hds[128*16];
  __shared__ unsigned long long red[4][16];

  float tot[64], reg[64];
  #pragma unroll
  for (int i = 0; i < 64; ++i) { tot[i] = 0.f; reg[i] = 0.f; }

  const float* hf = hist + (size_t)(t-64)*(HH*BB);

  #pragma unroll 1
  for (int kc8 = 0; kc8 < 8; ++kc8) {
    __syncthreads();
    #pragma unroll
    for (int s = 0; s < 8; ++s) {
      int idx = s*256 + tid;
      int kl = idx >> 4, bb = idx & 15;
      hds[idx] = hf[(size_t)(kc8*128 + kl)*BB + z*16 + bb];
    }
    __syncthreads();
    #pragma unroll 1
    for (int sub = 0; sub < 4; ++sub) {
      int kabs = kc8*128 + sub*32;
      if (kabs == 288 || kabs == 576 || kabs == 864) {
        #pragma unroll
        for (int i = 0; i < 64; ++i) { tot[i] = __fadd_rn(tot[i], reg[i]); reg[i] = 0.f; }
      }
      #pragma unroll 2
      for (int k = sub*32; k < sub*32 + 32; ++k) {
        const float* wr = Wo + (size_t)(kc8*128 + k)*VV;
        float wv0 = wr[vc[0]], wv1 = wr[vc[1]], wv2 = wr[vc[2]], wv3 = wr[vc[3]];
        #pragma unroll
        for (int bb = 0; bb < 16; ++bb) {
          float hb = hds[k*16 + bb];
          reg[0*16+bb] = __fadd_rn(reg[0*16+bb], __fmul_rn(hb, wv0));
          reg[1*16+bb] = __fadd_rn(reg[1*16+bb], __fmul_rn(hb, wv1));
          reg[2*16+bb] = __fadd_rn(reg[2*16+bb], __fmul_rn(hb, wv2));
          reg[3*16+bb] = __fadd_rn(reg[3*16+bb], __fmul_rn(hb, wv3));
        }
      }
    }
  }
  #pragma unroll
  for (int i = 0; i < 64; ++i) tot[i] = __fadd_rn(tot[i], reg[i]);

  uint32_t kt0, kt1;
  tf2x32(0u, 1u, 0u, (uint32_t)t, kt0, kt1);
  float bov[4];
  #pragma unroll
  for (int vj = 0; vj < 4; ++vj) bov[vj] = val[vj] ? bo[v[vj]] : 0.f;

  #pragma unroll 1
  for (int bb = 0; bb < 16; ++bb) {
    int bglob = z*16 + bb;
    unsigned long long pm = 0ull;
    #pragma unroll
    for (int vj = 0; vj < 4; ++vj) {
      if (val[vj]) {
        uint32_t y0, y1;
        tf2x32(kt0, kt1, 0u, (uint32_t)(bglob*VV + v[vj]), y0, y1);
        float u  = u01f(y0 ^ y1);
        float l1 = logf(u);
        float l2 = logf(-l1);
        float g  = -l2;
        float L  = __fadd_rn(tot[vj*16 + bb], bov[vj]);
        float sc = __fadd_rn(g, L);
        unsigned long long pk = pack32(sc, v[vj]);
        if (pk > pm) pm = pk;
      }
    }
    #pragma unroll
    for (int m = 32; m > 0; m >>= 1) {
      unsigned long long q = __shfl_xor(pm, m);
      if (q > pm) pm = q;
    }
    if (lane == 0) red[w][bb] = pm;
    __syncthreads();
    if (tid == 0) {
      unsigned long long m0 = red[0][bb];
      if (red[1][bb] > m0) m0 = red[1][bb];
      if (red[2][bb] > m0) m0 = red[2][bb];
      if (red[3][bb] > m0) m0 = red[3][bb];
      atomicMax(&best[(size_t)t*BB + z*16 + bb], m0);
    }
    __syncthreads();
  }
}

// ---------------- finalize ----------------
__global__ void finalize(const int* __restrict__ x, const int* __restrict__ gnp,
                         const unsigned long long* __restrict__ best, int* __restrict__ out)
{
  int i = blockIdx.x*256 + threadIdx.x;
  if (i >= BB*TT) return;
  int t = i & 127;
  int b = i >> 7;
  if (t < gnp[0] || t < 64) out[i] = x[i];
  else out[i] = 8191 - (int)(best[(size_t)t*BB + b] & 0x1FFFull);
}

// ---------------- launch ----------------
extern "C" void kernel_launch(void* const* d_in, const int* in_sizes, int n_in,
                              void* d_out, int out_size, void* d_ws, size_t ws_size,
                              hipStream_t stream)
{
  const int*   x    = (const int*)  d_in[0];
  const int*   gn   = (const int*)  d_in[1];
  const float* emb  = (const float*)d_in[2];
  const float* Wi   = (const float*)d_in[3];
  const float* Ui   = (const float*)d_in[4];
  const float* bi   = (const float*)d_in[5];
  const float* Wf   = (const float*)d_in[6];
  const float* Uf   = (const float*)d_in[7];
  const float* bf   = (const float*)d_in[8];
  const float* Wog  = (const float*)d_in[9];
  const float* Uog  = (const float*)d_in[10];
  const float* bog  = (const float*)d_in[11];
  const float* Wc   = (const float*)d_in[12];
  const float* Uc   = (const float*)d_in[13];
  const float* bc   = (const float*)d_in[14];
  const float* Wo   = (const float*)d_in[15];
  const float* bo   = (const float*)d_in[16];

  // ws: Ut 16MB | Wt 4MB | ring 512KB | hist 16MB | px 8MB | best 64KB | flags 1KB
  float* Ut   = (float*)d_ws;                              // 4Mi floats
  float* Wt   = Ut + (size_t)4*1024*1024;                  // 1Mi floats
  float* ring = Wt + (size_t)1024*1024;                    // 2*65536 floats
  float* hist = ring + (size_t)2*HH*BB;                    // 64*65536 floats
  float* px   = hist + (size_t)64*HH*BB;                   // 128*256*64 floats
  unsigned long long* best =
      (unsigned long long*)(px + (size_t)TT*EE*BB);        // 8192 u64
  int* flags  = (int*)(best + (size_t)TT*BB);              // 256 int

  initz<<<512, 256, 0, stream>>>(ring, best, flags);
  transpose4f<<<dim3(256,4), 256, 0, stream>>>(Ui, Uf, Uog, Uc, Ut, 1024, 1024);
  transpose4f<<<dim3(64,4),  256, 0, stream>>>(Wi, Wf, Wog, Wc, Wt, 256, 1024);
  pxgen<<<8192, 256, 0, stream>>>(x, emb, px);

  const float* Wtp = Wt; const float* Utp = Ut;
  const float* bip = bi; const float* bfp = bf; const float* bogp = bog; const float* bcp = bc;
  const float* pxp = px; float* ringp = ring; float* histp = hist; int* flagsp = flags;
  void* kargs[] = { (void*)&Wtp, (void*)&Utp,
                    (void*)&bip, (void*)&bfp, (void*)&bogp, (void*)&bcp,
                    (void*)&pxp, (void*)&ringp, (void*)&histp, (void*)&flagsp };
  hipLaunchCooperativeKernel((void*)lstm_rec, dim3(256), dim3(512), kargs, 0, stream);

  logits_samp<<<dim3(8,64,4), 256, 0, stream>>>(hist, Wo, bo, gn, best);
  finalize<<<32, 256, 0, stream>>>(x, gn, best, (int*)d_out);
}

// Round 5
// 7882.427 us; speedup vs baseline: 5.7180x; 5.7157x over previous
//
#include <hip/hip_runtime.h>
#include <hip/hip_cooperative_groups.h>
#include <cstdint>
#include <cstddef>

#define TT 128
#define BB 64
#define EE 256
#define HH 1024
#define VV 8000
#define LSTRIDE 132   // LDS row stride: 16B-aligned, 4i-bank starts (optimal b128)

// ---------------- threefry2x32 (20 rounds), bit-exact vs JAX partitionable ----------------
__device__ __forceinline__ uint32_t rotl32(uint32_t v, int r){ return (v<<r)|(v>>(32-r)); }

__device__ __forceinline__ void tf2x32(uint32_t k0, uint32_t k1, uint32_t x0, uint32_t x1,
                                       uint32_t& y0, uint32_t& y1)
{
  const uint32_t k2 = k0 ^ k1 ^ 0x1BD11BDAu;
  x0 += k0; x1 += k1;
#define TFR(r) { x0 += x1; x1 = rotl32(x1,(r)); x1 ^= x0; }
  TFR(13) TFR(15) TFR(26) TFR(6)   x0 += k1; x1 += k2 + 1u;
  TFR(17) TFR(29) TFR(16) TFR(24)  x0 += k2; x1 += k0 + 2u;
  TFR(13) TFR(15) TFR(26) TFR(6)   x0 += k0; x1 += k1 + 3u;
  TFR(17) TFR(29) TFR(16) TFR(24)  x0 += k1; x1 += k2 + 4u;
  TFR(13) TFR(15) TFR(26) TFR(6)   x0 += k2; x1 += k0 + 5u;
#undef TFR
  y0 = x0; y1 = x1;
}

// uniform in [tiny,1): bit-exact fp32 recipe of jax uniform(minval=tiny, maxval=1)
__device__ __forceinline__ float u01f(uint32_t bits){
  float f = __uint_as_float((bits >> 9) | 0x3f800000u) - 1.0f;
  return (f == 0.0f) ? 1.17549435e-38f : f;
}

// ---------------- XLA EmitFastTanh, non-FMA form (mul/add separate roundings) ------------
__device__ __forceinline__ float xla_tanh(float x){
  float xc = fminf(fmaxf(x, -7.90531110763549805f), 7.90531110763549805f);
  float x2 = __fmul_rn(xc, xc);
  float num = -2.76076847742355e-16f;
  num = __fadd_rn(__fmul_rn(x2, num),  2.00018790482477e-13f);
  num = __fadd_rn(__fmul_rn(x2, num), -8.60467152213735e-11f);
  num = __fadd_rn(__fmul_rn(x2, num),  5.12229709037114e-08f);
  num = __fadd_rn(__fmul_rn(x2, num),  1.48572235717979e-05f);
  num = __fadd_rn(__fmul_rn(x2, num),  6.37261928875436e-04f);
  num = __fadd_rn(__fmul_rn(x2, num),  4.89352455891786e-03f);
  num = __fmul_rn(xc, num);
  float den = 1.19825839466702e-06f;
  den = __fadd_rn(__fmul_rn(x2, den), 1.18534705686654e-04f);
  den = __fadd_rn(__fmul_rn(x2, den), 2.26843463243900e-03f);
  den = __fadd_rn(__fmul_rn(x2, den), 4.89352518554385e-03f);
  float r = __fdiv_rn(num, den);
  return (fabsf(x) < 0.0004f) ? x : r;
}

// XLA LogisticExpander: logistic(x) = 0.5 + 0.5*tanh(0.5*x), separate roundings
__device__ __forceinline__ float xla_sigmoid(float x){
  float t = xla_tanh(__fmul_rn(0.5f, x));
  return __fadd_rn(0.5f, __fmul_rn(0.5f, t));
}

// pack fp32 score + v; ties -> smaller v (first-max, matching jnp.argmax)
__device__ __forceinline__ unsigned long long pack32(float s, int v){
  uint32_t u = __float_as_uint(s);
  u = (u >> 31) ? ~u : (u | 0x80000000u);
  return ((unsigned long long)u << 32) | (unsigned)(8191 - v);
}

// ---------------- init ----------------
__global__ void initz(float* ring, unsigned long long* best, int* flags){
  int i = blockIdx.x*256 + threadIdx.x;
  if (i < 2*HH*BB) ring[i] = 0.f;
  if (i < TT*BB)   best[i] = 0ull;
  if (i < 256)     flags[i] = 0;
}

// ---------------- px precompute: px[t][e][b] = emb[x[b][t]][e] ----------------
__global__ __launch_bounds__(256) void pxgen(
    const int* __restrict__ x, const float* __restrict__ emb, float* __restrict__ px)
{
  int flat = blockIdx.x*256 + threadIdx.x;      // 128*256*64 = 2M
  int b = flat & 63;
  int e = (flat >> 6) & 255;
  int t = flat >> 14;
  if (t >= TT) return;
  int tok = x[b*TT + t];
  px[((size_t)t*EE + e)*BB + b] = emb[(size_t)tok*EE + e];
}

// ---------------- transpose 4 gate matrices: in [R][C] -> out[(g*C + c)*R + r] ----------------
__global__ __launch_bounds__(256) void transpose4f(
    const float* __restrict__ g0, const float* __restrict__ g1,
    const float* __restrict__ g2, const float* __restrict__ g3,
    float* __restrict__ out, int R, int C)
{
  const float* in = (blockIdx.y==0)?g0:(blockIdx.y==1)?g1:(blockIdx.y==2)?g2:g3;
  int tilesC = C >> 6;
  int tr = blockIdx.x / tilesC, tc = blockIdx.x % tilesC;
  __shared__ float tile[64][65];
  int tid = threadIdx.x;
  #pragma unroll
  for (int s = 0; s < 16; ++s) {
    int li = s*256 + tid;
    int r = li >> 6, c = li & 63;
    tile[r][c] = in[(size_t)(tr*64 + r)*C + tc*64 + c];
  }
  __syncthreads();
  #pragma unroll
  for (int s = 0; s < 16; ++s) {
    int li = s*256 + tid;
    int c = li >> 6, r = li & 63;
    out[((size_t)blockIdx.y*C + tc*64 + c)*R + tr*64 + r] = tile[r][c];
  }
}

// ---------------- cooperative LSTM recurrence: XLA-CPU faithful, fast transport -----------
// 256 blocks x 512 threads (8 waves). Wave w: p = w>>1 -> jc = bid*4+p; half = w&1 ->
// gates {i,f} (half0) or {og,c} (half1). Lanes = batch b. Each gate's mul/add chain is
// computed end-to-end by one thread => exact reference rounding (xw chain e=0..255;
// hU panels folded at k=288/576/864). Cross-XCD h transport via device-scope (agent)
// atomics through L3; per-block flag barrier (no L2 flush => weights stay L2-hot).
//
// R5 = exact R0 structure (known-good 7.13ms steady; R1-R4's barrier/prefetch rework
// regressed 6x via in-order vmcnt retirement and is fully reverted) + two fixes:
//  * LDS column XOR-swizzle col' = col ^ (((row>>3)&7)<<2) on BOTH staging tiles:
//    staging stores were 8-way bank-conflicted (5.87e8 conflict cycles/dispatch =
//    ~7.4us/step); swizzle makes stores 2-way (free, m136) and provably keeps the
//    b128 reads conflict-free (mask uniform within each 8-lane phase => rotation).
//    Pure bijective layout permutation per row -> bit-exactness untouched.
//  * hist store moved after the flag release store (off the pre-flag vmcnt0 drain).
__global__ __launch_bounds__(512, 2) void lstm_rec(
    const float* __restrict__ Wt, const float* __restrict__ Ut,
    const float* __restrict__ bi, const float* __restrict__ bf,
    const float* __restrict__ bog, const float* __restrict__ bc,
    const float* __restrict__ px, float* __restrict__ ring,
    float* __restrict__ hist, int* __restrict__ flags)
{
  __shared__ float sA[64*LSTRIDE];
  __shared__ float sB[64*LSTRIDE];
  __shared__ float spx[64*LSTRIDE];
  __shared__ float xch[512];

  const int tid  = threadIdx.x;
  const int w    = tid >> 6;
  const int lane = tid & 63;
  const int p    = w >> 1;
  const int half = w & 1;
  const int ju   = __builtin_amdgcn_readfirstlane(blockIdx.x*4 + p);
  const int g0   = 2*half, g1 = 2*half + 1;
  const int sw4  = ((lane >> 3) & 7) << 2;   // read-side column swizzle for row=lane

  const float* U0 = Ut + ((size_t)g0*HH + ju)*HH;
  const float* U1 = Ut + ((size_t)g1*HH + ju)*HH;
  const float* W0 = Wt + ((size_t)g0*HH + ju)*EE;
  const float* W1 = Wt + ((size_t)g1*HH + ju)*EE;
  const float biaA = half ? bog[ju] : bi[ju];
  const float biaB = half ? bc[ju]  : bf[ju];

  float c = 0.f;
  float B0 = 0.f, B1 = 0.f;   // xw+bias for my 2 gates
  float4 pre[4];

  auto load_chunk = [&](const float* hp, int hcn){
    #pragma unroll
    for (int s = 0; s < 4; ++s) {
      int f = s*512 + tid;
      int k = f >> 4, b0 = (f & 15)*4;
      const unsigned long long* gp =
          (const unsigned long long*)(hp + (size_t)(hcn*128 + k)*BB + b0);
      unsigned long long a0 = __hip_atomic_load(gp,   __ATOMIC_RELAXED, __HIP_MEMORY_SCOPE_AGENT);
      unsigned long long a1 = __hip_atomic_load(gp+1, __ATOMIC_RELAXED, __HIP_MEMORY_SCOPE_AGENT);
      pre[s].x = __uint_as_float((unsigned)a0);
      pre[s].y = __uint_as_float((unsigned)(a0 >> 32));
      pre[s].z = __uint_as_float((unsigned)a1);
      pre[s].w = __uint_as_float((unsigned)(a1 >> 32));
    }
  };
  // swizzled staging store: rows b0..b0+3 share (row>>3) (b0%8 in {0,4}, j<=3), so
  // one mask per s; store col kc = k ^ mask -> 2 lanes/bank (free) instead of 8-way
  auto store_chunk = [&](float* buf){
    #pragma unroll
    for (int s = 0; s < 4; ++s) {
      int f = s*512 + tid;
      int k = f >> 4, b0 = (f & 15)*4;
      int kc = k ^ (((b0 >> 3) & 7) << 2);
      buf[(b0+0)*LSTRIDE + kc] = pre[s].x;
      buf[(b0+1)*LSTRIDE + kc] = pre[s].y;
      buf[(b0+2)*LSTRIDE + kc] = pre[s].z;
      buf[(b0+3)*LSTRIDE + kc] = pre[s].w;
    }
  };

  // xw chains for my 2 gates at step t2 (exact e=0..255 mul/add order, then +bias)
  auto compute_xw = [&](int t2){
    float A0 = 0.f, A1 = 0.f;
    #pragma unroll 1
    for (int ch = 0; ch < 2; ++ch) {
      const float* pxc = px + ((size_t)t2*EE + ch*128)*BB;
      __syncthreads();
      #pragma unroll
      for (int s = 0; s < 4; ++s) {
        int f = s*512 + tid;
        int e = f >> 4, b0 = (f & 15)*4;
        float4 v = *(const float4*)(pxc + (size_t)e*BB + b0);
        int ec = e ^ (((b0 >> 3) & 7) << 2);
        spx[(b0+0)*LSTRIDE + ec] = v.x;
        spx[(b0+1)*LSTRIDE + ec] = v.y;
        spx[(b0+2)*LSTRIDE + ec] = v.z;
        spx[(b0+3)*LSTRIDE + ec] = v.w;
      }
      __syncthreads();
      #pragma unroll
      for (int e = 0; e < 128; e += 4) {
        float4 p4 = *(const float4*)&spx[lane*LSTRIDE + (e ^ sw4)];
        A0 = __fadd_rn(A0, __fmul_rn(p4.x, W0[ch*128 + e + 0]));
        A1 = __fadd_rn(A1, __fmul_rn(p4.x, W1[ch*128 + e + 0]));
        A0 = __fadd_rn(A0, __fmul_rn(p4.y, W0[ch*128 + e + 1]));
        A1 = __fadd_rn(A1, __fmul_rn(p4.y, W1[ch*128 + e + 1]));
        A0 = __fadd_rn(A0, __fmul_rn(p4.z, W0[ch*128 + e + 2]));
        A1 = __fadd_rn(A1, __fmul_rn(p4.z, W1[ch*128 + e + 2]));
        A0 = __fadd_rn(A0, __fmul_rn(p4.w, W0[ch*128 + e + 3]));
        A1 = __fadd_rn(A1, __fmul_rn(p4.w, W1[ch*128 + e + 3]));
      }
    }
    B0 = __fadd_rn(A0, biaA);
    B1 = __fadd_rn(A1, biaB);
  };

  compute_xw(0);   // prologue: xw for t=0

  #pragma unroll 1
  for (int t = 0; t < TT; ++t) {
    const float* hp = ring + (size_t)(t & 1)*(HH*BB);
    float*       rn = ring + (size_t)((t+1) & 1)*(HH*BB);

    // ---- h @ U: mul+add chains, Eigen kc=288 panels; LDS double-buffered ----
    load_chunk(hp, 0);
    float R0 = 0.f, R1 = 0.f, T0 = 0.f, T1 = 0.f;
    #pragma unroll 1
    for (int hc = 0; hc < 8; ++hc) {
      float* cur = (hc & 1) ? sB : sA;
      __syncthreads();
      store_chunk(cur);
      if (hc < 7) load_chunk(hp, hc + 1);
      __syncthreads();
      #pragma unroll
      for (int sub = 0; sub < 4; ++sub) {
        int kabs = hc*128 + sub*32;
        if (kabs == 288 || kabs == 576 || kabs == 864) {   // Eigen C += panel (CR add)
          T0 = __fadd_rn(T0, R0); R0 = 0.f;
          T1 = __fadd_rn(T1, R1); R1 = 0.f;
        }
        #pragma unroll
        for (int q = sub*32; q < sub*32 + 32; q += 4) {
          float4 h4 = *(const float4*)&cur[lane*LSTRIDE + (q ^ sw4)];
          R0 = __fadd_rn(R0, __fmul_rn(h4.x, U0[hc*128 + q + 0]));
          R1 = __fadd_rn(R1, __fmul_rn(h4.x, U1[hc*128 + q + 0]));
          R0 = __fadd_rn(R0, __fmul_rn(h4.y, U0[hc*128 + q + 1]));
          R1 = __fadd_rn(R1, __fmul_rn(h4.y, U1[hc*128 + q + 1]));
          R0 = __fadd_rn(R0, __fmul_rn(h4.z, U0[hc*128 + q + 2]));
          R1 = __fadd_rn(R1, __fmul_rn(h4.z, U1[hc*128 + q + 2]));
          R0 = __fadd_rn(R0, __fmul_rn(h4.w, U0[hc*128 + q + 3]));
          R1 = __fadd_rn(R1, __fmul_rn(h4.w, U1[hc*128 + q + 3]));
        }
      }
    }
    T0 = __fadd_rn(T0, R0);                 // final panel fold
    T1 = __fadd_rn(T1, R1);
    float z0 = __fadd_rn(B0, T0);           // z = fl(xw + hU)
    float z1 = __fadd_rn(B1, T1);

    // ---- gates: half1 computes tanh(zc), sig(zo); half0 computes sig(zi), sig(zf) ----
    float igv = 0.f, fgv = 0.f, hv = 0.f;
    if (half) {
      float th  = xla_tanh(z1);
      float ogs = xla_sigmoid(z0);
      xch[p*64 + lane]       = th;
      xch[256 + p*64 + lane] = ogs;
    } else {
      igv = xla_sigmoid(z0);
      fgv = xla_sigmoid(z1);
    }
    __syncthreads();
    if (!half) {
      float th  = xch[p*64 + lane];
      float ogs = xch[256 + p*64 + lane];
      c = __fadd_rn(__fmul_rn(fgv, c), __fmul_rn(igv, th));
      hv = __fmul_rn(ogs, xla_tanh(c));
      __hip_atomic_store(&rn[(size_t)ju*BB + lane], hv,
                         __ATOMIC_RELAXED, __HIP_MEMORY_SCOPE_AGENT);
    }
    __syncthreads();   // drain all waves' h stores (vmcnt0 before s_barrier)
    if (tid == 0)
      __hip_atomic_store(&flags[blockIdx.x], t+1, __ATOMIC_RELEASE, __HIP_MEMORY_SCOPE_AGENT);
    if (!half && t >= 64)                   // hist off the drain path; consumed post-kernel
      hist[(size_t)(t-64)*(HH*BB) + (size_t)ju*BB + lane] = hv;

    if (t < TT-1) {
      compute_xw(t+1);    // overlapped with other blocks finishing step t
      if (w == 0) {       // wave0 polls all 256 flags (4 per lane)
        for (;;) {
          int m0 = __hip_atomic_load(&flags[lane],       __ATOMIC_RELAXED, __HIP_MEMORY_SCOPE_AGENT);
          int m1 = __hip_atomic_load(&flags[64 + lane],  __ATOMIC_RELAXED, __HIP_MEMORY_SCOPE_AGENT);
          int m2 = __hip_atomic_load(&flags[128 + lane], __ATOMIC_RELAXED, __HIP_MEMORY_SCOPE_AGENT);
          int m3 = __hip_atomic_load(&flags[192 + lane], __ATOMIC_RELAXED, __HIP_MEMORY_SCOPE_AGENT);
          int mm = m0 < m1 ? m0 : m1;
          int nn = m2 < m3 ? m2 : m3;
          mm = mm < nn ? mm : nn;
          if (__all(mm >= t+1)) break;
          __builtin_amdgcn_s_sleep(1);
        }
        __atomic_signal_fence(__ATOMIC_ACQUIRE);
      }
      __syncthreads();
    }
  }
}

// ---------------- logits + gumbel argmax: XLA-CPU faithful (unchanged, verified) ----------
__global__ __launch_bounds__(256, 2) void logits_samp(
    const float* __restrict__ hist, const float* __restrict__ Wo,
    const float* __restrict__ bo, const int* __restrict__ gnp,
    unsigned long long* __restrict__ best)
{
  const int t = 64 + blockIdx.y;
  if (t < gnp[0]) return;
  const int vt   = blockIdx.x;     // [0,8)
  const int z    = blockIdx.z;     // [0,4) b-quarter
  const int tid  = threadIdx.x;
  const int w    = tid >> 6;
  const int lane = tid & 63;

  int v[4], vc[4]; bool val[4];
  #pragma unroll
  for (int vj = 0; vj < 4; ++vj) {
    v[vj]  = vt*1024 + vj*256 + tid;
    val[vj] = (v[vj] < VV);
    vc[vj] = val[vj] ? v[vj] : (VV-1);
  }

  __shared__ float hds[128*16];
  __shared__ unsigned long long red[4][16];

  float tot[64], reg[64];
  #pragma unroll
  for (int i = 0; i < 64; ++i) { tot[i] = 0.f; reg[i] = 0.f; }

  const float* hf = hist + (size_t)(t-64)*(HH*BB);

  #pragma unroll 1
  for (int kc8 = 0; kc8 < 8; ++kc8) {
    __syncthreads();
    #pragma unroll
    for (int s = 0; s < 8; ++s) {
      int idx = s*256 + tid;
      int kl = idx >> 4, bb = idx & 15;
      hds[idx] = hf[(size_t)(kc8*128 + kl)*BB + z*16 + bb];
    }
    __syncthreads();
    #pragma unroll 1
    for (int sub = 0; sub < 4; ++sub) {
      int kabs = kc8*128 + sub*32;
      if (kabs == 288 || kabs == 576 || kabs == 864) {
        #pragma unroll
        for (int i = 0; i < 64; ++i) { tot[i] = __fadd_rn(tot[i], reg[i]); reg[i] = 0.f; }
      }
      #pragma unroll 2
      for (int k = sub*32; k < sub*32 + 32; ++k) {
        const float* wr = Wo + (size_t)(kc8*128 + k)*VV;
        float wv0 = wr[vc[0]], wv1 = wr[vc[1]], wv2 = wr[vc[2]], wv3 = wr[vc[3]];
        #pragma unroll
        for (int bb = 0; bb < 16; ++bb) {
          float hb = hds[k*16 + bb];
          reg[0*16+bb] = __fadd_rn(reg[0*16+bb], __fmul_rn(hb, wv0));
          reg[1*16+bb] = __fadd_rn(reg[1*16+bb], __fmul_rn(hb, wv1));
          reg[2*16+bb] = __fadd_rn(reg[2*16+bb], __fmul_rn(hb, wv2));
          reg[3*16+bb] = __fadd_rn(reg[3*16+bb], __fmul_rn(hb, wv3));
        }
      }
    }
  }
  #pragma unroll
  for (int i = 0; i < 64; ++i) tot[i] = __fadd_rn(tot[i], reg[i]);

  uint32_t kt0, kt1;
  tf2x32(0u, 1u, 0u, (uint32_t)t, kt0, kt1);
  float bov[4];
  #pragma unroll
  for (int vj = 0; vj < 4; ++vj) bov[vj] = val[vj] ? bo[v[vj]] : 0.f;

  #pragma unroll 1
  for (int bb = 0; bb < 16; ++bb) {
    int bglob = z*16 + bb;
    unsigned long long pm = 0ull;
    #pragma unroll
    for (int vj = 0; vj < 4; ++vj) {
      if (val[vj]) {
        uint32_t y0, y1;
        tf2x32(kt0, kt1, 0u, (uint32_t)(bglob*VV + v[vj]), y0, y1);
        float u  = u01f(y0 ^ y1);
        float l1 = logf(u);
        float l2 = logf(-l1);
        float g  = -l2;
        float L  = __fadd_rn(tot[vj*16 + bb], bov[vj]);
        float sc = __fadd_rn(g, L);
        unsigned long long pk = pack32(sc, v[vj]);
        if (pk > pm) pm = pk;
      }
    }
    #pragma unroll
    for (int m = 32; m > 0; m >>= 1) {
      unsigned long long q = __shfl_xor(pm, m);
      if (q > pm) pm = q;
    }
    if (lane == 0) red[w][bb] = pm;
    __syncthreads();
    if (tid == 0) {
      unsigned long long m0 = red[0][bb];
      if (red[1][bb] > m0) m0 = red[1][bb];
      if (red[2][bb] > m0) m0 = red[2][bb];
      if (red[3][bb] > m0) m0 = red[3][bb];
      atomicMax(&best[(size_t)t*BB + z*16 + bb], m0);
    }
    __syncthreads();
  }
}

// ---------------- finalize ----------------
__global__ void finalize(const int* __restrict__ x, const int* __restrict__ gnp,
                         const unsigned long long* __restrict__ best, int* __restrict__ out)
{
  int i = blockIdx.x*256 + threadIdx.x;
  if (i >= BB*TT) return;
  int t = i & 127;
  int b = i >> 7;
  if (t < gnp[0] || t < 64) out[i] = x[i];
  else out[i] = 8191 - (int)(best[(size_t)t*BB + b] & 0x1FFFull);
}

// ---------------- launch ----------------
extern "C" void kernel_launch(void* const* d_in, const int* in_sizes, int n_in,
                              void* d_out, int out_size, void* d_ws, size_t ws_size,
                              hipStream_t stream)
{
  const int*   x    = (const int*)  d_in[0];
  const int*   gn   = (const int*)  d_in[1];
  const float* emb  = (const float*)d_in[2];
  const float* Wi   = (const float*)d_in[3];
  const float* Ui   = (const float*)d_in[4];
  const float* bi   = (const float*)d_in[5];
  const float* Wf   = (const float*)d_in[6];
  const float* Uf   = (const float*)d_in[7];
  const float* bf   = (const float*)d_in[8];
  const float* Wog  = (const float*)d_in[9];
  const float* Uog  = (const float*)d_in[10];
  const float* bog  = (const float*)d_in[11];
  const float* Wc   = (const float*)d_in[12];
  const float* Uc   = (const float*)d_in[13];
  const float* bc   = (const float*)d_in[14];
  const float* Wo   = (const float*)d_in[15];
  const float* bo   = (const float*)d_in[16];

  // ws: Ut 16MB | Wt 4MB | ring 512KB | hist 16MB | px 8MB | best 64KB | flags 1KB
  float* Ut   = (float*)d_ws;                              // 4Mi floats
  float* Wt   = Ut + (size_t)4*1024*1024;                  // 1Mi floats
  float* ring = Wt + (size_t)1024*1024;                    // 2*65536 floats
  float* hist = ring + (size_t)2*HH*BB;                    // 64*65536 floats
  float* px   = hist + (size_t)64*HH*BB;                   // 128*256*64 floats
  unsigned long long* best =
      (unsigned long long*)(px + (size_t)TT*EE*BB);        // 8192 u64
  int* flags  = (int*)(best + (size_t)TT*BB);              // 256 int

  initz<<<512, 256, 0, stream>>>(ring, best, flags);
  transpose4f<<<dim3(256,4), 256, 0, stream>>>(Ui, Uf, Uog, Uc, Ut, 1024, 1024);
  transpose4f<<<dim3(64,4),  256, 0, stream>>>(Wi, Wf, Wog, Wc, Wt, 256, 1024);
  pxgen<<<8192, 256, 0, stream>>>(x, emb, px);

  const float* Wtp = Wt; const float* Utp = Ut;
  const float* bip = bi; const float* bfp = bf; const float* bogp = bog; const float* bcp = bc;
  const float* pxp = px; float* ringp = ring; float* histp = hist; int* flagsp = flags;
  void* kargs[] = { (void*)&Wtp, (void*)&Utp,
                    (void*)&bip, (void*)&bfp, (void*)&bogp, (void*)&bcp,
                    (void*)&pxp, (void*)&ringp, (void*)&histp, (void*)&flagsp };
  hipLaunchCooperativeKernel((void*)lstm_rec, dim3(256), dim3(512), kargs, 0, stream);

  logits_samp<<<dim3(8,64,4), 256, 0, stream>>>(hist, Wo, bo, gn, best);
  finalize<<<32, 256, 0, stream>>>(x, gn, best, (int*)d_out);
}

// Round 6
// 7722.330 us; speedup vs baseline: 5.8365x; 1.0207x over previous
//
#include <hip/hip_runtime.h>
#include <hip/hip_cooperative_groups.h>
#include <cstdint>
#include <cstddef>

#define TT 128
#define BB 64
#define EE 256
#define HH 1024
#define VV 8000
#define LSTRIDE 132   // LDS row stride: 16B-aligned, 4i-bank starts (optimal b128)

// ---------------- threefry2x32 (20 rounds), bit-exact vs JAX partitionable ----------------
__device__ __forceinline__ uint32_t rotl32(uint32_t v, int r){ return (v<<r)|(v>>(32-r)); }

__device__ __forceinline__ void tf2x32(uint32_t k0, uint32_t k1, uint32_t x0, uint32_t x1,
                                       uint32_t& y0, uint32_t& y1)
{
  const uint32_t k2 = k0 ^ k1 ^ 0x1BD11BDAu;
  x0 += k0; x1 += k1;
#define TFR(r) { x0 += x1; x1 = rotl32(x1,(r)); x1 ^= x0; }
  TFR(13) TFR(15) TFR(26) TFR(6)   x0 += k1; x1 += k2 + 1u;
  TFR(17) TFR(29) TFR(16) TFR(24)  x0 += k2; x1 += k0 + 2u;
  TFR(13) TFR(15) TFR(26) TFR(6)   x0 += k0; x1 += k1 + 3u;
  TFR(17) TFR(29) TFR(16) TFR(24)  x0 += k1; x1 += k2 + 4u;
  TFR(13) TFR(15) TFR(26) TFR(6)   x0 += k2; x1 += k0 + 5u;
#undef TFR
  y0 = x0; y1 = x1;
}

// uniform in [tiny,1): bit-exact fp32 recipe of jax uniform(minval=tiny, maxval=1)
__device__ __forceinline__ float u01f(uint32_t bits){
  float f = __uint_as_float((bits >> 9) | 0x3f800000u) - 1.0f;
  return (f == 0.0f) ? 1.17549435e-38f : f;
}

// ---------------- XLA EmitFastTanh, non-FMA form (mul/add separate roundings) ------------
__device__ __forceinline__ float xla_tanh(float x){
  float xc = fminf(fmaxf(x, -7.90531110763549805f), 7.90531110763549805f);
  float x2 = __fmul_rn(xc, xc);
  float num = -2.76076847742355e-16f;
  num = __fadd_rn(__fmul_rn(x2, num),  2.00018790482477e-13f);
  num = __fadd_rn(__fmul_rn(x2, num), -8.60467152213735e-11f);
  num = __fadd_rn(__fmul_rn(x2, num),  5.12229709037114e-08f);
  num = __fadd_rn(__fmul_rn(x2, num),  1.48572235717979e-05f);
  num = __fadd_rn(__fmul_rn(x2, num),  6.37261928875436e-04f);
  num = __fadd_rn(__fmul_rn(x2, num),  4.89352455891786e-03f);
  num = __fmul_rn(xc, num);
  float den = 1.19825839466702e-06f;
  den = __fadd_rn(__fmul_rn(x2, den), 1.18534705686654e-04f);
  den = __fadd_rn(__fmul_rn(x2, den), 2.26843463243900e-03f);
  den = __fadd_rn(__fmul_rn(x2, den), 4.89352518554385e-03f);
  float r = __fdiv_rn(num, den);
  return (fabsf(x) < 0.0004f) ? x : r;
}

// XLA LogisticExpander: logistic(x) = 0.5 + 0.5*tanh(0.5*x), separate roundings
__device__ __forceinline__ float xla_sigmoid(float x){
  float t = xla_tanh(__fmul_rn(0.5f, x));
  return __fadd_rn(0.5f, __fmul_rn(0.5f, t));
}

// pack fp32 score + v; ties -> smaller v (first-max, matching jnp.argmax)
__device__ __forceinline__ unsigned long long pack32(float s, int v){
  uint32_t u = __float_as_uint(s);
  u = (u >> 31) ? ~u : (u | 0x80000000u);
  return ((unsigned long long)u << 32) | (unsigned)(8191 - v);
}

#define LGKM0 asm volatile("s_waitcnt lgkmcnt(0)" ::: "memory")

// ---------------- init ----------------
__global__ void initz(float* ring, unsigned long long* best, int* flags){
  int i = blockIdx.x*256 + threadIdx.x;
  if (i < 2*HH*BB) ring[i] = 0.f;
  if (i < TT*BB)   best[i] = 0ull;
  if (i < 256)     flags[i] = 0;
}

// ---------------- px precompute: px[t][e][b] = emb[x[b][t]][e] ----------------
__global__ __launch_bounds__(256) void pxgen(
    const int* __restrict__ x, const float* __restrict__ emb, float* __restrict__ px)
{
  int flat = blockIdx.x*256 + threadIdx.x;      // 128*256*64 = 2M
  int b = flat & 63;
  int e = (flat >> 6) & 255;
  int t = flat >> 14;
  if (t >= TT) return;
  int tok = x[b*TT + t];
  px[((size_t)t*EE + e)*BB + b] = emb[(size_t)tok*EE + e];
}

// ---------------- transpose 4 gate matrices: in [R][C] -> out[(g*C + c)*R + r] ----------------
__global__ __launch_bounds__(256) void transpose4f(
    const float* __restrict__ g0, const float* __restrict__ g1,
    const float* __restrict__ g2, const float* __restrict__ g3,
    float* __restrict__ out, int R, int C)
{
  const float* in = (blockIdx.y==0)?g0:(blockIdx.y==1)?g1:(blockIdx.y==2)?g2:g3;
  int tilesC = C >> 6;
  int tr = blockIdx.x / tilesC, tc = blockIdx.x % tilesC;
  __shared__ float tile[64][65];
  int tid = threadIdx.x;
  #pragma unroll
  for (int s = 0; s < 16; ++s) {
    int li = s*256 + tid;
    int r = li >> 6, c = li & 63;
    tile[r][c] = in[(size_t)(tr*64 + r)*C + tc*64 + c];
  }
  __syncthreads();
  #pragma unroll
  for (int s = 0; s < 16; ++s) {
    int li = s*256 + tid;
    int c = li >> 6, r = li & 63;
    out[((size_t)blockIdx.y*C + tc*64 + c)*R + tr*64 + r] = tile[r][c];
  }
}

// ---------------- cooperative LSTM recurrence: XLA-CPU faithful, fast transport -----------
// 256 blocks x 512 threads (8 waves). Wave w: p = w>>1 -> jc = bid*4+p; half = w&1 ->
// gates {i,f} (half0) or {og,c} (half1). Lanes = batch b. Each gate's mul/add chain is
// computed end-to-end by one thread => exact reference rounding (xw chain e=0..255;
// hU panels folded at k=288/576/864). Cross-XCD h transport via device-scope (agent)
// atomics through L3; per-block flag barrier (no L2 flush => weights stay L2-hot).
//
// R6 = R5 (verified: swizzled staging, 6.79ms steady) with hot-loop barriers changed
// from __syncthreads (which drains vmcnt(0), forcing chunk hc+1's L3-fabric loads to
// complete before MAC(hc) starts) to raw s_barrier + lgkmcnt(0)-only:
//  * h-loop: ONE barrier per chunk (double-buffered sA/sB: arrival at bar(hc-1)
//    transitively implies MAC(hc-2) retired, so the WAR barrier is redundant).
//    Prefetch loads stay in flight across the barrier; next store_chunk waits on
//    them via register deps (counted vmcnt), hidden under MAC.
//  * xw staging + xch exchange: lgkm-only barriers (LDS-only hazards).
//  * __syncthreads kept ONLY before the flag release (h visibility needs the vmcnt
//    drain) and after the poll. Register footprint identical to R5 (pre[4] body).
__global__ __launch_bounds__(512, 2) void lstm_rec(
    const float* __restrict__ Wt, const float* __restrict__ Ut,
    const float* __restrict__ bi, const float* __restrict__ bf,
    const float* __restrict__ bog, const float* __restrict__ bc,
    const float* __restrict__ px, float* __restrict__ ring,
    float* __restrict__ hist, int* __restrict__ flags)
{
  __shared__ float sA[64*LSTRIDE];
  __shared__ float sB[64*LSTRIDE];
  __shared__ float spx[64*LSTRIDE];
  __shared__ float xch[512];

  const int tid  = threadIdx.x;
  const int w    = tid >> 6;
  const int lane = tid & 63;
  const int p    = w >> 1;
  const int half = w & 1;
  const int ju   = __builtin_amdgcn_readfirstlane(blockIdx.x*4 + p);
  const int g0   = 2*half, g1 = 2*half + 1;
  const int sw4  = ((lane >> 3) & 7) << 2;   // read-side column swizzle for row=lane

  const float* U0 = Ut + ((size_t)g0*HH + ju)*HH;
  const float* U1 = Ut + ((size_t)g1*HH + ju)*HH;
  const float* W0 = Wt + ((size_t)g0*HH + ju)*EE;
  const float* W1 = Wt + ((size_t)g1*HH + ju)*EE;
  const float biaA = half ? bog[ju] : bi[ju];
  const float biaB = half ? bc[ju]  : bf[ju];

  float c = 0.f;
  float B0 = 0.f, B1 = 0.f;   // xw+bias for my 2 gates
  float4 pre[4];

  auto load_chunk = [&](const float* hp, int hcn){
    #pragma unroll
    for (int s = 0; s < 4; ++s) {
      int f = s*512 + tid;
      int k = f >> 4, b0 = (f & 15)*4;
      const unsigned long long* gp =
          (const unsigned long long*)(hp + (size_t)(hcn*128 + k)*BB + b0);
      unsigned long long a0 = __hip_atomic_load(gp,   __ATOMIC_RELAXED, __HIP_MEMORY_SCOPE_AGENT);
      unsigned long long a1 = __hip_atomic_load(gp+1, __ATOMIC_RELAXED, __HIP_MEMORY_SCOPE_AGENT);
      pre[s].x = __uint_as_float((unsigned)a0);
      pre[s].y = __uint_as_float((unsigned)(a0 >> 32));
      pre[s].z = __uint_as_float((unsigned)a1);
      pre[s].w = __uint_as_float((unsigned)(a1 >> 32));
    }
  };
  // swizzled staging store: rows b0..b0+3 share (row>>3) (b0%8 in {0,4}, j<=3), so
  // one mask per s; store col kc = k ^ mask -> 2 lanes/bank (free) instead of 8-way
  auto store_chunk = [&](float* buf){
    #pragma unroll
    for (int s = 0; s < 4; ++s) {
      int f = s*512 + tid;
      int k = f >> 4, b0 = (f & 15)*4;
      int kc = k ^ (((b0 >> 3) & 7) << 2);
      buf[(b0+0)*LSTRIDE + kc] = pre[s].x;
      buf[(b0+1)*LSTRIDE + kc] = pre[s].y;
      buf[(b0+2)*LSTRIDE + kc] = pre[s].z;
      buf[(b0+3)*LSTRIDE + kc] = pre[s].w;
    }
  };

  // xw chains for my 2 gates at step t2 (exact e=0..255 mul/add order, then +bias)
  auto compute_xw = [&](int t2){
    float A0 = 0.f, A1 = 0.f;
    #pragma unroll 1
    for (int ch = 0; ch < 2; ++ch) {
      const float* pxc = px + ((size_t)t2*EE + ch*128)*BB;
      LGKM0;                                  // prior spx readers retired (program order)
      __builtin_amdgcn_s_barrier();           // WAR: all waves done reading spx
      #pragma unroll
      for (int s = 0; s < 4; ++s) {
        int f = s*512 + tid;
        int e = f >> 4, b0 = (f & 15)*4;
        float4 v = *(const float4*)(pxc + (size_t)e*BB + b0);
        int ec = e ^ (((b0 >> 3) & 7) << 2);
        spx[(b0+0)*LSTRIDE + ec] = v.x;
        spx[(b0+1)*LSTRIDE + ec] = v.y;
        spx[(b0+2)*LSTRIDE + ec] = v.z;
        spx[(b0+3)*LSTRIDE + ec] = v.w;
      }
      LGKM0;                                  // staging writes retired
      __builtin_amdgcn_s_barrier();           // RAW: spx visible to all waves
      #pragma unroll
      for (int e = 0; e < 128; e += 4) {
        float4 p4 = *(const float4*)&spx[lane*LSTRIDE + (e ^ sw4)];
        A0 = __fadd_rn(A0, __fmul_rn(p4.x, W0[ch*128 + e + 0]));
        A1 = __fadd_rn(A1, __fmul_rn(p4.x, W1[ch*128 + e + 0]));
        A0 = __fadd_rn(A0, __fmul_rn(p4.y, W0[ch*128 + e + 1]));
        A1 = __fadd_rn(A1, __fmul_rn(p4.y, W1[ch*128 + e + 1]));
        A0 = __fadd_rn(A0, __fmul_rn(p4.z, W0[ch*128 + e + 2]));
        A1 = __fadd_rn(A1, __fmul_rn(p4.z, W1[ch*128 + e + 2]));
        A0 = __fadd_rn(A0, __fmul_rn(p4.w, W0[ch*128 + e + 3]));
        A1 = __fadd_rn(A1, __fmul_rn(p4.w, W1[ch*128 + e + 3]));
      }
    }
    B0 = __fadd_rn(A0, biaA);
    B1 = __fadd_rn(A1, biaB);
  };

  compute_xw(0);   // prologue: xw for t=0

  #pragma unroll 1
  for (int t = 0; t < TT; ++t) {
    const float* hp = ring + (size_t)(t & 1)*(HH*BB);
    float*       rn = ring + (size_t)((t+1) & 1)*(HH*BB);

    // ---- h @ U: 1 raw barrier/chunk; vmcnt never drained in this loop ----
    load_chunk(hp, 0);
    float R0 = 0.f, R1 = 0.f, T0 = 0.f, T1 = 0.f;
    #pragma unroll 1
    for (int hc = 0; hc < 8; ++hc) {
      float* cur = (hc & 1) ? sB : sA;
      store_chunk(cur);                    // waits pre deps (counted vmcnt, not 0)
      if (hc < 7) load_chunk(hp, hc + 1);  // prefetch stays in flight across barrier
      LGKM0;                               // staging writes retired
      __builtin_amdgcn_s_barrier();        // (WAR on cur guaranteed by bar(hc-1))
      #pragma unroll
      for (int sub = 0; sub < 4; ++sub) {
        int kabs = hc*128 + sub*32;
        if (kabs == 288 || kabs == 576 || kabs == 864) {   // Eigen C += panel (CR add)
          T0 = __fadd_rn(T0, R0); R0 = 0.f;
          T1 = __fadd_rn(T1, R1); R1 = 0.f;
        }
        #pragma unroll
        for (int q = sub*32; q < sub*32 + 32; q += 4) {
          float4 h4 = *(const float4*)&cur[lane*LSTRIDE + (q ^ sw4)];
          R0 = __fadd_rn(R0, __fmul_rn(h4.x, U0[hc*128 + q + 0]));
          R1 = __fadd_rn(R1, __fmul_rn(h4.x, U1[hc*128 + q + 0]));
          R0 = __fadd_rn(R0, __fmul_rn(h4.y, U0[hc*128 + q + 1]));
          R1 = __fadd_rn(R1, __fmul_rn(h4.y, U1[hc*128 + q + 1]));
          R0 = __fadd_rn(R0, __fmul_rn(h4.z, U0[hc*128 + q + 2]));
          R1 = __fadd_rn(R1, __fmul_rn(h4.z, U1[hc*128 + q + 2]));
          R0 = __fadd_rn(R0, __fmul_rn(h4.w, U0[hc*128 + q + 3]));
          R1 = __fadd_rn(R1, __fmul_rn(h4.w, U1[hc*128 + q + 3]));
        }
      }
    }
    T0 = __fadd_rn(T0, R0);                 // final panel fold
    T1 = __fadd_rn(T1, R1);
    float z0 = __fadd_rn(B0, T0);           // z = fl(xw + hU)
    float z1 = __fadd_rn(B1, T1);

    // ---- gates: half1 computes tanh(zc), sig(zo); half0 computes sig(zi), sig(zf) ----
    float igv = 0.f, fgv = 0.f, hv = 0.f;
    if (half) {
      float th  = xla_tanh(z1);
      float ogs = xla_sigmoid(z0);
      xch[p*64 + lane]       = th;
      xch[256 + p*64 + lane] = ogs;
    } else {
      igv = xla_sigmoid(z0);
      fgv = xla_sigmoid(z1);
    }
    LGKM0;
    __builtin_amdgcn_s_barrier();           // xch visible (LDS-only hazard)
    if (!half) {
      float th  = xch[p*64 + lane];
      float ogs = xch[256 + p*64 + lane];
      c = __fadd_rn(__fmul_rn(fgv, c), __fmul_rn(igv, th));
      hv = __fmul_rn(ogs, xla_tanh(c));
      __hip_atomic_store(&rn[(size_t)ju*BB + lane], hv,
                         __ATOMIC_RELAXED, __HIP_MEMORY_SCOPE_AGENT);
    }
    __syncthreads();   // REQUIRED vmcnt(0) drain: all waves' h stores done before flag
    if (tid == 0)
      __hip_atomic_store(&flags[blockIdx.x], t+1, __ATOMIC_RELEASE, __HIP_MEMORY_SCOPE_AGENT);
    if (!half && t >= 64)                   // hist off the drain path; consumed post-kernel
      hist[(size_t)(t-64)*(HH*BB) + (size_t)ju*BB + lane] = hv;

    if (t < TT-1) {
      compute_xw(t+1);    // overlapped with other blocks finishing step t
      if (w == 0) {       // wave0 polls all 256 flags (4 per lane)
        for (;;) {
          int m0 = __hip_atomic_load(&flags[lane],       __ATOMIC_RELAXED, __HIP_MEMORY_SCOPE_AGENT);
          int m1 = __hip_atomic_load(&flags[64 + lane],  __ATOMIC_RELAXED, __HIP_MEMORY_SCOPE_AGENT);
          int m2 = __hip_atomic_load(&flags[128 + lane], __ATOMIC_RELAXED, __HIP_MEMORY_SCOPE_AGENT);
          int m3 = __hip_atomic_load(&flags[192 + lane], __ATOMIC_RELAXED, __HIP_MEMORY_SCOPE_AGENT);
          int mm = m0 < m1 ? m0 : m1;
          int nn = m2 < m3 ? m2 : m3;
          mm = mm < nn ? mm : nn;
          if (__all(mm >= t+1)) break;
          __builtin_amdgcn_s_sleep(1);
        }
        __atomic_signal_fence(__ATOMIC_ACQUIRE);
      }
      __syncthreads();
    }
  }
}

// ---------------- logits + gumbel argmax: XLA-CPU faithful (unchanged, verified) ----------
__global__ __launch_bounds__(256, 2) void logits_samp(
    const float* __restrict__ hist, const float* __restrict__ Wo,
    const float* __restrict__ bo, const int* __restrict__ gnp,
    unsigned long long* __restrict__ best)
{
  const int t = 64 + blockIdx.y;
  if (t < gnp[0]) return;
  const int vt   = blockIdx.x;     // [0,8)
  const int z    = blockIdx.z;     // [0,4) b-quarter
  const int tid  = threadIdx.x;
  const int w    = tid >> 6;
  const int lane = tid & 63;

  int v[4], vc[4]; bool val[4];
  #pragma unroll
  for (int vj = 0; vj < 4; ++vj) {
    v[vj]  = vt*1024 + vj*256 + tid;
    val[vj] = (v[vj] < VV);
    vc[vj] = val[vj] ? v[vj] : (VV-1);
  }

  __shared__ float hds[128*16];
  __shared__ unsigned long long red[4][16];

  float tot[64], reg[64];
  #pragma unroll
  for (int i = 0; i < 64; ++i) { tot[i] = 0.f; reg[i] = 0.f; }

  const float* hf = hist + (size_t)(t-64)*(HH*BB);

  #pragma unroll 1
  for (int kc8 = 0; kc8 < 8; ++kc8) {
    __syncthreads();
    #pragma unroll
    for (int s = 0; s < 8; ++s) {
      int idx = s*256 + tid;
      int kl = idx >> 4, bb = idx & 15;
      hds[idx] = hf[(size_t)(kc8*128 + kl)*BB + z*16 + bb];
    }
    __syncthreads();
    #pragma unroll 1
    for (int sub = 0; sub < 4; ++sub) {
      int kabs = kc8*128 + sub*32;
      if (kabs == 288 || kabs == 576 || kabs == 864) {
        #pragma unroll
        for (int i = 0; i < 64; ++i) { tot[i] = __fadd_rn(tot[i], reg[i]); reg[i] = 0.f; }
      }
      #pragma unroll 2
      for (int k = sub*32; k < sub*32 + 32; ++k) {
        const float* wr = Wo + (size_t)(kc8*128 + k)*VV;
        float wv0 = wr[vc[0]], wv1 = wr[vc[1]], wv2 = wr[vc[2]], wv3 = wr[vc[3]];
        #pragma unroll
        for (int bb = 0; bb < 16; ++bb) {
          float hb = hds[k*16 + bb];
          reg[0*16+bb] = __fadd_rn(reg[0*16+bb], __fmul_rn(hb, wv0));
          reg[1*16+bb] = __fadd_rn(reg[1*16+bb], __fmul_rn(hb, wv1));
          reg[2*16+bb] = __fadd_rn(reg[2*16+bb], __fmul_rn(hb, wv2));
          reg[3*16+bb] = __fadd_rn(reg[3*16+bb], __fmul_rn(hb, wv3));
        }
      }
    }
  }
  #pragma unroll
  for (int i = 0; i < 64; ++i) tot[i] = __fadd_rn(tot[i], reg[i]);

  uint32_t kt0, kt1;
  tf2x32(0u, 1u, 0u, (uint32_t)t, kt0, kt1);
  float bov[4];
  #pragma unroll
  for (int vj = 0; vj < 4; ++vj) bov[vj] = val[vj] ? bo[v[vj]] : 0.f;

  #pragma unroll 1
  for (int bb = 0; bb < 16; ++bb) {
    int bglob = z*16 + bb;
    unsigned long long pm = 0ull;
    #pragma unroll
    for (int vj = 0; vj < 4; ++vj) {
      if (val[vj]) {
        uint32_t y0, y1;
        tf2x32(kt0, kt1, 0u, (uint32_t)(bglob*VV + v[vj]), y0, y1);
        float u  = u01f(y0 ^ y1);
        float l1 = logf(u);
        float l2 = logf(-l1);
        float g  = -l2;
        float L  = __fadd_rn(tot[vj*16 + bb], bov[vj]);
        float sc = __fadd_rn(g, L);
        unsigned long long pk = pack32(sc, v[vj]);
        if (pk > pm) pm = pk;
      }
    }
    #pragma unroll
    for (int m = 32; m > 0; m >>= 1) {
      unsigned long long q = __shfl_xor(pm, m);
      if (q > pm) pm = q;
    }
    if (lane == 0) red[w][bb] = pm;
    __syncthreads();
    if (tid == 0) {
      unsigned long long m0 = red[0][bb];
      if (red[1][bb] > m0) m0 = red[1][bb];
      if (red[2][bb] > m0) m0 = red[2][bb];
      if (red[3][bb] > m0) m0 = red[3][bb];
      atomicMax(&best[(size_t)t*BB + z*16 + bb], m0);
    }
    __syncthreads();
  }
}

// ---------------- finalize ----------------
__global__ void finalize(const int* __restrict__ x, const int* __restrict__ gnp,
                         const unsigned long long* __restrict__ best, int* __restrict__ out)
{
  int i = blockIdx.x*256 + threadIdx.x;
  if (i >= BB*TT) return;
  int t = i & 127;
  int b = i >> 7;
  if (t < gnp[0] || t < 64) out[i] = x[i];
  else out[i] = 8191 - (int)(best[(size_t)t*BB + b] & 0x1FFFull);
}

// ---------------- launch ----------------
extern "C" void kernel_launch(void* const* d_in, const int* in_sizes, int n_in,
                              void* d_out, int out_size, void* d_ws, size_t ws_size,
                              hipStream_t stream)
{
  const int*   x    = (const int*)  d_in[0];
  const int*   gn   = (const int*)  d_in[1];
  const float* emb  = (const float*)d_in[2];
  const float* Wi   = (const float*)d_in[3];
  const float* Ui   = (const float*)d_in[4];
  const float* bi   = (const float*)d_in[5];
  const float* Wf   = (const float*)d_in[6];
  const float* Uf   = (const float*)d_in[7];
  const float* bf   = (const float*)d_in[8];
  const float* Wog  = (const float*)d_in[9];
  const float* Uog  = (const float*)d_in[10];
  const float* bog  = (const float*)d_in[11];
  const float* Wc   = (const float*)d_in[12];
  const float* Uc   = (const float*)d_in[13];
  const float* bc   = (const float*)d_in[14];
  const float* Wo   = (const float*)d_in[15];
  const float* bo   = (const float*)d_in[16];

  // ws: Ut 16MB | Wt 4MB | ring 512KB | hist 16MB | px 8MB | best 64KB | flags 1KB
  float* Ut   = (float*)d_ws;                              // 4Mi floats
  float* Wt   = Ut + (size_t)4*1024*1024;                  // 1Mi floats
  float* ring = Wt + (size_t)1024*1024;                    // 2*65536 floats
  float* hist = ring + (size_t)2*HH*BB;                    // 64*65536 floats
  float* px   = hist + (size_t)64*HH*BB;                   // 128*256*64 floats
  unsigned long long* best =
      (unsigned long long*)(px + (size_t)TT*EE*BB);        // 8192 u64
  int* flags  = (int*)(best + (size_t)TT*BB);              // 256 int

  initz<<<512, 256, 0, stream>>>(ring, best, flags);
  transpose4f<<<dim3(256,4), 256, 0, stream>>>(Ui, Uf, Uog, Uc, Ut, 1024, 1024);
  transpose4f<<<dim3(64,4),  256, 0, stream>>>(Wi, Wf, Wog, Wc, Wt, 256, 1024);
  pxgen<<<8192, 256, 0, stream>>>(x, emb, px);

  const float* Wtp = Wt; const float* Utp = Ut;
  const float* bip = bi; const float* bfp = bf; const float* bogp = bog; const float* bcp = bc;
  const float* pxp = px; float* ringp = ring; float* histp = hist; int* flagsp = flags;
  void* kargs[] = { (void*)&Wtp, (void*)&Utp,
                    (void*)&bip, (void*)&bfp, (void*)&bogp, (void*)&bcp,
                    (void*)&pxp, (void*)&ringp, (void*)&histp, (void*)&flagsp };
  hipLaunchCooperativeKernel((void*)lstm_rec, dim3(256), dim3(512), kargs, 0, stream);

  logits_samp<<<dim3(8,64,4), 256, 0, stream>>>(hist, Wo, bo, gn, best);
  finalize<<<32, 256, 0, stream>>>(x, gn, best, (int*)d_out);
}

// Round 7
// 7406.245 us; speedup vs baseline: 6.0856x; 1.0427x over previous
//
#include <hip/hip_runtime.h>
#include <hip/hip_cooperative_groups.h>
#include <cstdint>
#include <cstddef>

#define TT 128
#define BB 64
#define EE 256
#define HH 1024
#define VV 8000
#define LSTRIDE 132   // LDS row stride: 16B-aligned, 4i-bank starts (optimal b128)

// ---------------- threefry2x32 (20 rounds), bit-exact vs JAX partitionable ----------------
__device__ __forceinline__ uint32_t rotl32(uint32_t v, int r){ return (v<<r)|(v>>(32-r)); }

__device__ __forceinline__ void tf2x32(uint32_t k0, uint32_t k1, uint32_t x0, uint32_t x1,
                                       uint32_t& y0, uint32_t& y1)
{
  const uint32_t k2 = k0 ^ k1 ^ 0x1BD11BDAu;
  x0 += k0; x1 += k1;
#define TFR(r) { x0 += x1; x1 = rotl32(x1,(r)); x1 ^= x0; }
  TFR(13) TFR(15) TFR(26) TFR(6)   x0 += k1; x1 += k2 + 1u;
  TFR(17) TFR(29) TFR(16) TFR(24)  x0 += k2; x1 += k0 + 2u;
  TFR(13) TFR(15) TFR(26) TFR(6)   x0 += k0; x1 += k1 + 3u;
  TFR(17) TFR(29) TFR(16) TFR(24)  x0 += k1; x1 += k2 + 4u;
  TFR(13) TFR(15) TFR(26) TFR(6)   x0 += k2; x1 += k0 + 5u;
#undef TFR
  y0 = x0; y1 = x1;
}

// uniform in [tiny,1): bit-exact fp32 recipe of jax uniform(minval=tiny, maxval=1)
__device__ __forceinline__ float u01f(uint32_t bits){
  float f = __uint_as_float((bits >> 9) | 0x3f800000u) - 1.0f;
  return (f == 0.0f) ? 1.17549435e-38f : f;
}

// ---------------- XLA EmitFastTanh, non-FMA form (mul/add separate roundings) ------------
__device__ __forceinline__ float xla_tanh(float x){
  float xc = fminf(fmaxf(x, -7.90531110763549805f), 7.90531110763549805f);
  float x2 = __fmul_rn(xc, xc);
  float num = -2.76076847742355e-16f;
  num = __fadd_rn(__fmul_rn(x2, num),  2.00018790482477e-13f);
  num = __fadd_rn(__fmul_rn(x2, num), -8.60467152213735e-11f);
  num = __fadd_rn(__fmul_rn(x2, num),  5.12229709037114e-08f);
  num = __fadd_rn(__fmul_rn(x2, num),  1.48572235717979e-05f);
  num = __fadd_rn(__fmul_rn(x2, num),  6.37261928875436e-04f);
  num = __fadd_rn(__fmul_rn(x2, num),  4.89352455891786e-03f);
  num = __fmul_rn(xc, num);
  float den = 1.19825839466702e-06f;
  den = __fadd_rn(__fmul_rn(x2, den), 1.18534705686654e-04f);
  den = __fadd_rn(__fmul_rn(x2, den), 2.26843463243900e-03f);
  den = __fadd_rn(__fmul_rn(x2, den), 4.89352518554385e-03f);
  float r = __fdiv_rn(num, den);
  return (fabsf(x) < 0.0004f) ? x : r;
}

// XLA LogisticExpander: logistic(x) = 0.5 + 0.5*tanh(0.5*x), separate roundings
__device__ __forceinline__ float xla_sigmoid(float x){
  float t = xla_tanh(__fmul_rn(0.5f, x));
  return __fadd_rn(0.5f, __fmul_rn(0.5f, t));
}

// pack fp32 score + v; ties -> smaller v (first-max, matching jnp.argmax)
__device__ __forceinline__ unsigned long long pack32(float s, int v){
  uint32_t u = __float_as_uint(s);
  u = (u >> 31) ? ~u : (u | 0x80000000u);
  return ((unsigned long long)u << 32) | (unsigned)(8191 - v);
}

#define LGKM0 asm volatile("s_waitcnt lgkmcnt(0)" ::: "memory")

// ---------------- init ----------------
__global__ void initz(float* hfull, unsigned long long* best, int* flags){
  int i = blockIdx.x*256 + threadIdx.x;
  if (i < HH*BB)  hfull[i] = 0.f;          // slot 0 = h(-1) = 0
  if (i < TT*BB)  best[i] = 0ull;
  if (i < 256)    flags[i] = 0;
}

// ---------------- px precompute: px[t][e][b] = emb[x[b][t]][e] ----------------
__global__ __launch_bounds__(256) void pxgen(
    const int* __restrict__ x, const float* __restrict__ emb, float* __restrict__ px)
{
  int flat = blockIdx.x*256 + threadIdx.x;      // 128*256*64 = 2M
  int b = flat & 63;
  int e = (flat >> 6) & 255;
  int t = flat >> 14;
  if (t >= TT) return;
  int tok = x[b*TT + t];
  px[((size_t)t*EE + e)*BB + b] = emb[(size_t)tok*EE + e];
}

// ---------------- transpose 4 gate matrices: in [R][C] -> out[(g*C + c)*R + r] ----------------
__global__ __launch_bounds__(256) void transpose4f(
    const float* __restrict__ g0, const float* __restrict__ g1,
    const float* __restrict__ g2, const float* __restrict__ g3,
    float* __restrict__ out, int R, int C)
{
  const float* in = (blockIdx.y==0)?g0:(blockIdx.y==1)?g1:(blockIdx.y==2)?g2:g3;
  int tilesC = C >> 6;
  int tr = blockIdx.x / tilesC, tc = blockIdx.x % tilesC;
  __shared__ float tile[64][65];
  int tid = threadIdx.x;
  #pragma unroll
  for (int s = 0; s < 16; ++s) {
    int li = s*256 + tid;
    int r = li >> 6, c = li & 63;
    tile[r][c] = in[(size_t)(tr*64 + r)*C + tc*64 + c];
  }
  __syncthreads();
  #pragma unroll
  for (int s = 0; s < 16; ++s) {
    int li = s*256 + tid;
    int c = li >> 6, r = li & 63;
    out[((size_t)blockIdx.y*C + tc*64 + c)*R + tr*64 + r] = tile[r][c];
  }
}

// ---------------- cooperative LSTM recurrence: XLA-CPU faithful, fast transport -----------
// 256 blocks x 512 threads (8 waves). Wave w: p = w>>1 -> jc = bid*4+p; half = w&1 ->
// gates {i,f} (half0) or {og,c} (half1). Lanes = batch b. Each gate's mul/add chain is
// computed end-to-end by one thread => exact reference rounding (xw chain e=0..255;
// hU panels folded at k=288/576/864).
//
// R7 transport redesign: h lives in a WRITE-ONCE buffer hfull[(TT+1)][1024][64]
// (slot 0 = h(-1)=0; step t writes slot t+1 with agent-scope stores + release flag,
// reads slot t with PLAIN cacheable float4 loads). Rationale: agent-scope loads
// bypass L1/L2, so the old depth-2 ring re-read 256KB/block/step over the L3
// fabric = 64MB/step at ~900cy latency -- the dominant stall (R6: 32us/step
// unexplained). Write-once addressing makes plain loads safe (no address is ever
// cached before its unique write: first touch is flag-gated), so each h line is
// fetched once per XCD and served L2-hot to the other 31 CUs (2MB/step fabric,
// 32x less). hfull doubles as hist: logits_samp reads h(t) at slot t+1, and the
// separate hist write disappears. Falsifier: absmax!=0 => cache staleness (L2
// prefetch into unwritten slots) => revert to agent loads.
// Barrier structure = R6 (verified): raw s_barrier + lgkmcnt-only in hot loop,
// __syncthreads only around the flag release / poll.
__global__ __launch_bounds__(512, 2) void lstm_rec(
    const float* __restrict__ Wt, const float* __restrict__ Ut,
    const float* __restrict__ bi, const float* __restrict__ bf,
    const float* __restrict__ bog, const float* __restrict__ bc,
    const float* __restrict__ px, float* __restrict__ hfull,
    int* __restrict__ flags)
{
  __shared__ float sA[64*LSTRIDE];
  __shared__ float sB[64*LSTRIDE];
  __shared__ float spx[64*LSTRIDE];
  __shared__ float xch[512];

  const int tid  = threadIdx.x;
  const int w    = tid >> 6;
  const int lane = tid & 63;
  const int p    = w >> 1;
  const int half = w & 1;
  const int ju   = __builtin_amdgcn_readfirstlane(blockIdx.x*4 + p);
  const int g0   = 2*half, g1 = 2*half + 1;
  const int sw4  = ((lane >> 3) & 7) << 2;   // read-side column swizzle for row=lane

  const float* U0 = Ut + ((size_t)g0*HH + ju)*HH;
  const float* U1 = Ut + ((size_t)g1*HH + ju)*HH;
  const float* W0 = Wt + ((size_t)g0*HH + ju)*EE;
  const float* W1 = Wt + ((size_t)g1*HH + ju)*EE;
  const float biaA = half ? bog[ju] : bi[ju];
  const float biaB = half ? bc[ju]  : bf[ju];

  float c = 0.f;
  float B0 = 0.f, B1 = 0.f;   // xw+bias for my 2 gates
  float4 pre[4];

  // plain cacheable vector loads: 4x float4 per thread (16B/lane, fully coalesced);
  // safe because hfull is write-once and first-touched only after the flag (no
  // stale line can exist in L1/L2)
  auto load_chunk = [&](const float* hp, int hcn){
    #pragma unroll
    for (int s = 0; s < 4; ++s) {
      int f = s*512 + tid;
      int k = f >> 4, b0 = (f & 15)*4;
      pre[s] = *(const float4*)(hp + (size_t)(hcn*128 + k)*BB + b0);
    }
  };
  // swizzled staging store: rows b0..b0+3 share (row>>3) (b0%8 in {0,4}, j<=3), so
  // one mask per s; store col kc = k ^ mask -> 2 lanes/bank (free) instead of 8-way
  auto store_chunk = [&](float* buf){
    #pragma unroll
    for (int s = 0; s < 4; ++s) {
      int f = s*512 + tid;
      int k = f >> 4, b0 = (f & 15)*4;
      int kc = k ^ (((b0 >> 3) & 7) << 2);
      buf[(b0+0)*LSTRIDE + kc] = pre[s].x;
      buf[(b0+1)*LSTRIDE + kc] = pre[s].y;
      buf[(b0+2)*LSTRIDE + kc] = pre[s].z;
      buf[(b0+3)*LSTRIDE + kc] = pre[s].w;
    }
  };

  // xw chains for my 2 gates at step t2 (exact e=0..255 mul/add order, then +bias)
  auto compute_xw = [&](int t2){
    float A0 = 0.f, A1 = 0.f;
    #pragma unroll 1
    for (int ch = 0; ch < 2; ++ch) {
      const float* pxc = px + ((size_t)t2*EE + ch*128)*BB;
      LGKM0;                                  // prior spx readers retired (program order)
      __builtin_amdgcn_s_barrier();           // WAR: all waves done reading spx
      #pragma unroll
      for (int s = 0; s < 4; ++s) {
        int f = s*512 + tid;
        int e = f >> 4, b0 = (f & 15)*4;
        float4 v = *(const float4*)(pxc + (size_t)e*BB + b0);
        int ec = e ^ (((b0 >> 3) & 7) << 2);
        spx[(b0+0)*LSTRIDE + ec] = v.x;
        spx[(b0+1)*LSTRIDE + ec] = v.y;
        spx[(b0+2)*LSTRIDE + ec] = v.z;
        spx[(b0+3)*LSTRIDE + ec] = v.w;
      }
      LGKM0;                                  // staging writes retired
      __builtin_amdgcn_s_barrier();           // RAW: spx visible to all waves
      #pragma unroll
      for (int e = 0; e < 128; e += 4) {
        float4 p4 = *(const float4*)&spx[lane*LSTRIDE + (e ^ sw4)];
        A0 = __fadd_rn(A0, __fmul_rn(p4.x, W0[ch*128 + e + 0]));
        A1 = __fadd_rn(A1, __fmul_rn(p4.x, W1[ch*128 + e + 0]));
        A0 = __fadd_rn(A0, __fmul_rn(p4.y, W0[ch*128 + e + 1]));
        A1 = __fadd_rn(A1, __fmul_rn(p4.y, W1[ch*128 + e + 1]));
        A0 = __fadd_rn(A0, __fmul_rn(p4.z, W0[ch*128 + e + 2]));
        A1 = __fadd_rn(A1, __fmul_rn(p4.z, W1[ch*128 + e + 2]));
        A0 = __fadd_rn(A0, __fmul_rn(p4.w, W0[ch*128 + e + 3]));
        A1 = __fadd_rn(A1, __fmul_rn(p4.w, W1[ch*128 + e + 3]));
      }
    }
    B0 = __fadd_rn(A0, biaA);
    B1 = __fadd_rn(A1, biaB);
  };

  compute_xw(0);   // prologue: xw for t=0

  #pragma unroll 1
  for (int t = 0; t < TT; ++t) {
    const float* hp = hfull + (size_t)t*(HH*BB);        // h(t-1), write-once slot
    float*       rn = hfull + (size_t)(t+1)*(HH*BB);    // h(t) destination

    // ---- h @ U: 1 raw barrier/chunk; vmcnt never drained in this loop ----
    load_chunk(hp, 0);
    float R0 = 0.f, R1 = 0.f, T0 = 0.f, T1 = 0.f;
    #pragma unroll 1
    for (int hc = 0; hc < 8; ++hc) {
      float* cur = (hc & 1) ? sB : sA;
      store_chunk(cur);                    // waits pre deps (counted vmcnt, not 0)
      if (hc < 7) load_chunk(hp, hc + 1);  // prefetch stays in flight across barrier
      LGKM0;                               // staging writes retired
      __builtin_amdgcn_s_barrier();        // (WAR on cur guaranteed by bar(hc-1))
      #pragma unroll
      for (int sub = 0; sub < 4; ++sub) {
        int kabs = hc*128 + sub*32;
        if (kabs == 288 || kabs == 576 || kabs == 864) {   // Eigen C += panel (CR add)
          T0 = __fadd_rn(T0, R0); R0 = 0.f;
          T1 = __fadd_rn(T1, R1); R1 = 0.f;
        }
        #pragma unroll
        for (int q = sub*32; q < sub*32 + 32; q += 4) {
          float4 h4 = *(const float4*)&cur[lane*LSTRIDE + (q ^ sw4)];
          R0 = __fadd_rn(R0, __fmul_rn(h4.x, U0[hc*128 + q + 0]));
          R1 = __fadd_rn(R1, __fmul_rn(h4.x, U1[hc*128 + q + 0]));
          R0 = __fadd_rn(R0, __fmul_rn(h4.y, U0[hc*128 + q + 1]));
          R1 = __fadd_rn(R1, __fmul_rn(h4.y, U1[hc*128 + q + 1]));
          R0 = __fadd_rn(R0, __fmul_rn(h4.z, U0[hc*128 + q + 2]));
          R1 = __fadd_rn(R1, __fmul_rn(h4.z, U1[hc*128 + q + 2]));
          R0 = __fadd_rn(R0, __fmul_rn(h4.w, U0[hc*128 + q + 3]));
          R1 = __fadd_rn(R1, __fmul_rn(h4.w, U1[hc*128 + q + 3]));
        }
      }
    }
    T0 = __fadd_rn(T0, R0);                 // final panel fold
    T1 = __fadd_rn(T1, R1);
    float z0 = __fadd_rn(B0, T0);           // z = fl(xw + hU)
    float z1 = __fadd_rn(B1, T1);

    // ---- gates: half1 computes tanh(zc), sig(zo); half0 computes sig(zi), sig(zf) ----
    float igv = 0.f, fgv = 0.f, hv = 0.f;
    if (half) {
      float th  = xla_tanh(z1);
      float ogs = xla_sigmoid(z0);
      xch[p*64 + lane]       = th;
      xch[256 + p*64 + lane] = ogs;
    } else {
      igv = xla_sigmoid(z0);
      fgv = xla_sigmoid(z1);
    }
    LGKM0;
    __builtin_amdgcn_s_barrier();           // xch visible (LDS-only hazard)
    if (!half) {
      float th  = xch[p*64 + lane];
      float ogs = xch[256 + p*64 + lane];
      c = __fadd_rn(__fmul_rn(fgv, c), __fmul_rn(igv, th));
      hv = __fmul_rn(ogs, xla_tanh(c));
      __hip_atomic_store(&rn[(size_t)ju*BB + lane], hv,
                         __ATOMIC_RELAXED, __HIP_MEMORY_SCOPE_AGENT);
    }
    __syncthreads();   // REQUIRED vmcnt(0) drain: all waves' h stores done before flag
    if (tid == 0)
      __hip_atomic_store(&flags[blockIdx.x], t+1, __ATOMIC_RELEASE, __HIP_MEMORY_SCOPE_AGENT);

    if (t < TT-1) {
      compute_xw(t+1);    // overlapped with other blocks finishing step t
      if (w == 0) {       // wave0 polls all 256 flags (4 per lane)
        for (;;) {
          int m0 = __hip_atomic_load(&flags[lane],       __ATOMIC_RELAXED, __HIP_MEMORY_SCOPE_AGENT);
          int m1 = __hip_atomic_load(&flags[64 + lane],  __ATOMIC_RELAXED, __HIP_MEMORY_SCOPE_AGENT);
          int m2 = __hip_atomic_load(&flags[128 + lane], __ATOMIC_RELAXED, __HIP_MEMORY_SCOPE_AGENT);
          int m3 = __hip_atomic_load(&flags[192 + lane], __ATOMIC_RELAXED, __HIP_MEMORY_SCOPE_AGENT);
          int mm = m0 < m1 ? m0 : m1;
          int nn = m2 < m3 ? m2 : m3;
          mm = mm < nn ? mm : nn;
          if (__all(mm >= t+1)) break;
          __builtin_amdgcn_s_sleep(1);
        }
        __atomic_signal_fence(__ATOMIC_ACQUIRE);
      }
      __syncthreads();
    }
  }
}

// ---------------- logits + gumbel argmax: XLA-CPU faithful (reads hfull slot t+1) -------
__global__ __launch_bounds__(256, 2) void logits_samp(
    const float* __restrict__ hfull, const float* __restrict__ Wo,
    const float* __restrict__ bo, const int* __restrict__ gnp,
    unsigned long long* __restrict__ best)
{
  const int t = 64 + blockIdx.y;
  if (t < gnp[0]) return;
  const int vt   = blockIdx.x;     // [0,8)
  const int z    = blockIdx.z;     // [0,4) b-quarter
  const int tid  = threadIdx.x;
  const int w    = tid >> 6;
  const int lane = tid & 63;

  int v[4], vc[4]; bool val[4];
  #pragma unroll
  for (int vj = 0; vj < 4; ++vj) {
    v[vj]  = vt*1024 + vj*256 + tid;
    val[vj] = (v[vj] < VV);
    vc[vj] = val[vj] ? v[vj] : (VV-1);
  }

  __shared__ float hds[128*16];
  __shared__ unsigned long long red[4][16];

  float tot[64], reg[64];
  #pragma unroll
  for (int i = 0; i < 64; ++i) { tot[i] = 0.f; reg[i] = 0.f; }

  const float* hf = hfull + (size_t)(t+1)*(HH*BB);   // h(t) lives in slot t+1

  #pragma unroll 1
  for (int kc8 = 0; kc8 < 8; ++kc8) {
    __syncthreads();
    #pragma unroll
    for (int s = 0; s < 8; ++s) {
      int idx = s*256 + tid;
      int kl = idx >> 4, bb = idx & 15;
      hds[idx] = hf[(size_t)(kc8*128 + kl)*BB + z*16 + bb];
    }
    __syncthreads();
    #pragma unroll 1
    for (int sub = 0; sub < 4; ++sub) {
      int kabs = kc8*128 + sub*32;
      if (kabs == 288 || kabs == 576 || kabs == 864) {
        #pragma unroll
        for (int i = 0; i < 64; ++i) { tot[i] = __fadd_rn(tot[i], reg[i]); reg[i] = 0.f; }
      }
      #pragma unroll 2
      for (int k = sub*32; k < sub*32 + 32; ++k) {
        const float* wr = Wo + (size_t)(kc8*128 + k)*VV;
        float wv0 = wr[vc[0]], wv1 = wr[vc[1]], wv2 = wr[vc[2]], wv3 = wr[vc[3]];
        #pragma unroll
        for (int bb = 0; bb < 16; ++bb) {
          float hb = hds[k*16 + bb];
          reg[0*16+bb] = __fadd_rn(reg[0*16+bb], __fmul_rn(hb, wv0));
          reg[1*16+bb] = __fadd_rn(reg[1*16+bb], __fmul_rn(hb, wv1));
          reg[2*16+bb] = __fadd_rn(reg[2*16+bb], __fmul_rn(hb, wv2));
          reg[3*16+bb] = __fadd_rn(reg[3*16+bb], __fmul_rn(hb, wv3));
        }
      }
    }
  }
  #pragma unroll
  for (int i = 0; i < 64; ++i) tot[i] = __fadd_rn(tot[i], reg[i]);

  uint32_t kt0, kt1;
  tf2x32(0u, 1u, 0u, (uint32_t)t, kt0, kt1);
  float bov[4];
  #pragma unroll
  for (int vj = 0; vj < 4; ++vj) bov[vj] = val[vj] ? bo[v[vj]] : 0.f;

  #pragma unroll 1
  for (int bb = 0; bb < 16; ++bb) {
    int bglob = z*16 + bb;
    unsigned long long pm = 0ull;
    #pragma unroll
    for (int vj = 0; vj < 4; ++vj) {
      if (val[vj]) {
        uint32_t y0, y1;
        tf2x32(kt0, kt1, 0u, (uint32_t)(bglob*VV + v[vj]), y0, y1);
        float u  = u01f(y0 ^ y1);
        float l1 = logf(u);
        float l2 = logf(-l1);
        float g  = -l2;
        float L  = __fadd_rn(tot[vj*16 + bb], bov[vj]);
        float sc = __fadd_rn(g, L);
        unsigned long long pk = pack32(sc, v[vj]);
        if (pk > pm) pm = pk;
      }
    }
    #pragma unroll
    for (int m = 32; m > 0; m >>= 1) {
      unsigned long long q = __shfl_xor(pm, m);
      if (q > pm) pm = q;
    }
    if (lane == 0) red[w][bb] = pm;
    __syncthreads();
    if (tid == 0) {
      unsigned long long m0 = red[0][bb];
      if (red[1][bb] > m0) m0 = red[1][bb];
      if (red[2][bb] > m0) m0 = red[2][bb];
      if (red[3][bb] > m0) m0 = red[3][bb];
      atomicMax(&best[(size_t)t*BB + z*16 + bb], m0);
    }
    __syncthreads();
  }
}

// ---------------- finalize ----------------
__global__ void finalize(const int* __restrict__ x, const int* __restrict__ gnp,
                         const unsigned long long* __restrict__ best, int* __restrict__ out)
{
  int i = blockIdx.x*256 + threadIdx.x;
  if (i >= BB*TT) return;
  int t = i & 127;
  int b = i >> 7;
  if (t < gnp[0] || t < 64) out[i] = x[i];
  else out[i] = 8191 - (int)(best[(size_t)t*BB + b] & 0x1FFFull);
}

// ---------------- launch ----------------
extern "C" void kernel_launch(void* const* d_in, const int* in_sizes, int n_in,
                              void* d_out, int out_size, void* d_ws, size_t ws_size,
                              hipStream_t stream)
{
  const int*   x    = (const int*)  d_in[0];
  const int*   gn   = (const int*)  d_in[1];
  const float* emb  = (const float*)d_in[2];
  const float* Wi   = (const float*)d_in[3];
  const float* Ui   = (const float*)d_in[4];
  const float* bi   = (const float*)d_in[5];
  const float* Wf   = (const float*)d_in[6];
  const float* Uf   = (const float*)d_in[7];
  const float* bf   = (const float*)d_in[8];
  const float* Wog  = (const float*)d_in[9];
  const float* Uog  = (const float*)d_in[10];
  const float* bog  = (const float*)d_in[11];
  const float* Wc   = (const float*)d_in[12];
  const float* Uc   = (const float*)d_in[13];
  const float* bc   = (const float*)d_in[14];
  const float* Wo   = (const float*)d_in[15];
  const float* bo   = (const float*)d_in[16];

  // ws: Ut 16MB | Wt 4MB | hfull 32.25MB (129 write-once h slots; doubles as hist)
  //     | px 8MB | best 64KB | flags 1KB   (~60.3MB total)
  float* Ut    = (float*)d_ws;                             // 4Mi floats
  float* Wt    = Ut + (size_t)4*1024*1024;                 // 1Mi floats
  float* hfull = Wt + (size_t)1024*1024;                   // 129*65536 floats
  float* px    = hfull + (size_t)(TT+1)*HH*BB;             // 128*256*64 floats
  unsigned long long* best =
      (unsigned long long*)(px + (size_t)TT*EE*BB);        // 8192 u64
  int* flags  = (int*)(best + (size_t)TT*BB);              // 256 int

  initz<<<512, 256, 0, stream>>>(hfull, best, flags);
  transpose4f<<<dim3(256,4), 256, 0, stream>>>(Ui, Uf, Uog, Uc, Ut, 1024, 1024);
  transpose4f<<<dim3(64,4),  256, 0, stream>>>(Wi, Wf, Wog, Wc, Wt, 256, 1024);
  pxgen<<<8192, 256, 0, stream>>>(x, emb, px);

  const float* Wtp = Wt; const float* Utp = Ut;
  const float* bip = bi; const float* bfp = bf; const float* bogp = bog; const float* bcp = bc;
  const float* pxp = px; float* hfullp = hfull; int* flagsp = flags;
  void* kargs[] = { (void*)&Wtp, (void*)&Utp,
                    (void*)&bip, (void*)&bfp, (void*)&bogp, (void*)&bcp,
                    (void*)&pxp, (void*)&hfullp, (void*)&flagsp };
  hipLaunchCooperativeKernel((void*)lstm_rec, dim3(256), dim3(512), kargs, 0, stream);

  logits_samp<<<dim3(8,64,4), 256, 0, stream>>>(hfull, Wo, bo, gn, best);
  finalize<<<32, 256, 0, stream>>>(x, gn, best, (int*)d_out);
}

// Round 12
// 7394.663 us; speedup vs baseline: 6.0951x; 1.0016x over previous
//
#include <hip/hip_runtime.h>
#include <hip/hip_cooperative_groups.h>
#include <cstdint>
#include <cstddef>

#define TT 128
#define BB 64
#define EE 256
#define HH 1024
#define VV 8000
#define LSTRIDE 132   // LDS row stride: 16B-aligned, 4i-bank starts (optimal b128)

// ---------------- threefry2x32 (20 rounds), bit-exact vs JAX partitionable ----------------
__device__ __forceinline__ uint32_t rotl32(uint32_t v, int r){ return (v<<r)|(v>>(32-r)); }

__device__ __forceinline__ void tf2x32(uint32_t k0, uint32_t k1, uint32_t x0, uint32_t x1,
                                       uint32_t& y0, uint32_t& y1)
{
  const uint32_t k2 = k0 ^ k1 ^ 0x1BD11BDAu;
  x0 += k0; x1 += k1;
#define TFR(r) { x0 += x1; x1 = rotl32(x1,(r)); x1 ^= x0; }
  TFR(13) TFR(15) TFR(26) TFR(6)   x0 += k1; x1 += k2 + 1u;
  TFR(17) TFR(29) TFR(16) TFR(24)  x0 += k2; x1 += k0 + 2u;
  TFR(13) TFR(15) TFR(26) TFR(6)   x0 += k0; x1 += k1 + 3u;
  TFR(17) TFR(29) TFR(16) TFR(24)  x0 += k1; x1 += k2 + 4u;
  TFR(13) TFR(15) TFR(26) TFR(6)   x0 += k2; x1 += k0 + 5u;
#undef TFR
  y0 = x0; y1 = x1;
}

// uniform in [tiny,1): bit-exact fp32 recipe of jax uniform(minval=tiny, maxval=1)
__device__ __forceinline__ float u01f(uint32_t bits){
  float f = __uint_as_float((bits >> 9) | 0x3f800000u) - 1.0f;
  return (f == 0.0f) ? 1.17549435e-38f : f;
}

// ---------------- XLA EmitFastTanh, non-FMA form (mul/add separate roundings) ------------
__device__ __forceinline__ float xla_tanh(float x){
  float xc = fminf(fmaxf(x, -7.90531110763549805f), 7.90531110763549805f);
  float x2 = __fmul_rn(xc, xc);
  float num = -2.76076847742355e-16f;
  num = __fadd_rn(__fmul_rn(x2, num),  2.00018790482477e-13f);
  num = __fadd_rn(__fmul_rn(x2, num), -8.60467152213735e-11f);
  num = __fadd_rn(__fmul_rn(x2, num),  5.12229709037114e-08f);
  num = __fadd_rn(__fmul_rn(x2, num),  1.48572235717979e-05f);
  num = __fadd_rn(__fmul_rn(x2, num),  6.37261928875436e-04f);
  num = __fadd_rn(__fmul_rn(x2, num),  4.89352455891786e-03f);
  num = __fmul_rn(xc, num);
  float den = 1.19825839466702e-06f;
  den = __fadd_rn(__fmul_rn(x2, den), 1.18534705686654e-04f);
  den = __fadd_rn(__fmul_rn(x2, den), 2.26843463243900e-03f);
  den = __fadd_rn(__fmul_rn(x2, den), 4.89352518554385e-03f);
  float r = __fdiv_rn(num, den);
  return (fabsf(x) < 0.0004f) ? x : r;
}

// XLA LogisticExpander: logistic(x) = 0.5 + 0.5*tanh(0.5*x), separate roundings
__device__ __forceinline__ float xla_sigmoid(float x){
  float t = xla_tanh(__fmul_rn(0.5f, x));
  return __fadd_rn(0.5f, __fmul_rn(0.5f, t));
}

// pack fp32 score + v; ties -> smaller v (first-max, matching jnp.argmax)
__device__ __forceinline__ unsigned long long pack32(float s, int v){
  uint32_t u = __float_as_uint(s);
  u = (u >> 31) ? ~u : (u | 0x80000000u);
  return ((unsigned long long)u << 32) | (unsigned)(8191 - v);
}

#define LGKM0 asm volatile("s_waitcnt lgkmcnt(0)" ::: "memory")

// ---------------- init ----------------
__global__ void initz(float* hfull, unsigned long long* best, int* flags){
  int i = blockIdx.x*256 + threadIdx.x;
  if (i < HH*BB)  hfull[i] = 0.f;          // slot 0 = h(-1) = 0
  if (i < TT*BB)  best[i] = 0ull;
  if (i < 256)    flags[i] = 0;
}

// ---------------- px precompute: px[t][e][b] = emb[x[b][t]][e] ----------------
__global__ __launch_bounds__(256) void pxgen(
    const int* __restrict__ x, const float* __restrict__ emb, float* __restrict__ px)
{
  int flat = blockIdx.x*256 + threadIdx.x;      // 128*256*64 = 2M
  int b = flat & 63;
  int e = (flat >> 6) & 255;
  int t = flat >> 14;
  if (t >= TT) return;
  int tok = x[b*TT + t];
  px[((size_t)t*EE + e)*BB + b] = emb[(size_t)tok*EE + e];
}

// ---------------- transpose 4 gate matrices: in [R][C] -> out[(g*C + c)*R + r] ----------------
__global__ __launch_bounds__(256) void transpose4f(
    const float* __restrict__ g0, const float* __restrict__ g1,
    const float* __restrict__ g2, const float* __restrict__ g3,
    float* __restrict__ out, int R, int C)
{
  const float* in = (blockIdx.y==0)?g0:(blockIdx.y==1)?g1:(blockIdx.y==2)?g2:g3;
  int tilesC = C >> 6;
  int tr = blockIdx.x / tilesC, tc = blockIdx.x % tilesC;
  __shared__ float tile[64][65];
  int tid = threadIdx.x;
  #pragma unroll
  for (int s = 0; s < 16; ++s) {
    int li = s*256 + tid;
    int r = li >> 6, c = li & 63;
    tile[r][c] = in[(size_t)(tr*64 + r)*C + tc*64 + c];
  }
  __syncthreads();
  #pragma unroll
  for (int s = 0; s < 16; ++s) {
    int li = s*256 + tid;
    int c = li >> 6, r = li & 63;
    out[((size_t)blockIdx.y*C + tc*64 + c)*R + tr*64 + r] = tile[r][c];
  }
}

// ---------------- cooperative LSTM recurrence: XLA-CPU faithful, fast transport -----------
// 256 blocks x 512 threads (8 waves). Wave w: p = w>>1 -> jc = bid*4+p; half = w&1 ->
// gates {i,f} (half0) or {og,c} (half1). Lanes = batch b. Each gate's mul/add chain is
// computed end-to-end by one thread => exact reference rounding (xw chain e=0..255;
// hU panels folded at k=288/576/864).
//
// R7 transport (verified): h lives in a WRITE-ONCE buffer hfull[(TT+1)][1024][64]
// (slot 0 = h(-1)=0; step t writes slot t+1 with agent-scope stores + release flag,
// reads slot t with PLAIN cacheable float4 loads). Write-once addressing makes plain
// loads safe (first touch is flag-gated), so each h line is fetched once per XCD and
// served L2-hot. hfull doubles as hist: logits_samp reads h(t) at slot t+1.
// Barrier structure (verified): raw s_barrier + lgkmcnt-only in hot loop,
// __syncthreads only around the flag release / poll.
// NOTE (R8-R11): all 16-wave/one-gate-per-wave restructures (1024-thr and
// 512-thr x 512-block variants) fail with an identical lstm-never-ran signature;
// mechanism not isolatable without launch-error visibility. This 8-wave body is
// the verified optimum of this session.
__global__ __launch_bounds__(512, 2) void lstm_rec(
    const float* __restrict__ Wt, const float* __restrict__ Ut,
    const float* __restrict__ bi, const float* __restrict__ bf,
    const float* __restrict__ bog, const float* __restrict__ bc,
    const float* __restrict__ px, float* __restrict__ hfull,
    int* __restrict__ flags)
{
  __shared__ float sA[64*LSTRIDE];
  __shared__ float sB[64*LSTRIDE];
  __shared__ float spx[64*LSTRIDE];
  __shared__ float xch[512];

  const int tid  = threadIdx.x;
  const int w    = tid >> 6;
  const int lane = tid & 63;
  const int p    = w >> 1;
  const int half = w & 1;
  const int ju   = __builtin_amdgcn_readfirstlane(blockIdx.x*4 + p);
  const int g0   = 2*half, g1 = 2*half + 1;
  const int sw4  = ((lane >> 3) & 7) << 2;   // read-side column swizzle for row=lane

  const float* U0 = Ut + ((size_t)g0*HH + ju)*HH;
  const float* U1 = Ut + ((size_t)g1*HH + ju)*HH;
  const float* W0 = Wt + ((size_t)g0*HH + ju)*EE;
  const float* W1 = Wt + ((size_t)g1*HH + ju)*EE;
  const float biaA = half ? bog[ju] : bi[ju];
  const float biaB = half ? bc[ju]  : bf[ju];

  float c = 0.f;
  float B0 = 0.f, B1 = 0.f;   // xw+bias for my 2 gates
  float4 pre[4];

  // plain cacheable vector loads: 4x float4 per thread (16B/lane, fully coalesced);
  // safe because hfull is write-once and first-touched only after the flag
  auto load_chunk = [&](const float* hp, int hcn){
    #pragma unroll
    for (int s = 0; s < 4; ++s) {
      int f = s*512 + tid;
      int k = f >> 4, b0 = (f & 15)*4;
      pre[s] = *(const float4*)(hp + (size_t)(hcn*128 + k)*BB + b0);
    }
  };
  // swizzled staging store: rows b0..b0+3 share (row>>3) (b0%8 in {0,4}, j<=3), so
  // one mask per s; store col kc = k ^ mask -> 2 lanes/bank (free) instead of 8-way
  auto store_chunk = [&](float* buf){
    #pragma unroll
    for (int s = 0; s < 4; ++s) {
      int f = s*512 + tid;
      int k = f >> 4, b0 = (f & 15)*4;
      int kc = k ^ (((b0 >> 3) & 7) << 2);
      buf[(b0+0)*LSTRIDE + kc] = pre[s].x;
      buf[(b0+1)*LSTRIDE + kc] = pre[s].y;
      buf[(b0+2)*LSTRIDE + kc] = pre[s].z;
      buf[(b0+3)*LSTRIDE + kc] = pre[s].w;
    }
  };

  // xw chains for my 2 gates at step t2 (exact e=0..255 mul/add order, then +bias)
  auto compute_xw = [&](int t2){
    float A0 = 0.f, A1 = 0.f;
    #pragma unroll 1
    for (int ch = 0; ch < 2; ++ch) {
      const float* pxc = px + ((size_t)t2*EE + ch*128)*BB;
      LGKM0;                                  // prior spx readers retired (program order)
      __builtin_amdgcn_s_barrier();           // WAR: all waves done reading spx
      #pragma unroll
      for (int s = 0; s < 4; ++s) {
        int f = s*512 + tid;
        int e = f >> 4, b0 = (f & 15)*4;
        float4 v = *(const float4*)(pxc + (size_t)e*BB + b0);
        int ec = e ^ (((b0 >> 3) & 7) << 2);
        spx[(b0+0)*LSTRIDE + ec] = v.x;
        spx[(b0+1)*LSTRIDE + ec] = v.y;
        spx[(b0+2)*LSTRIDE + ec] = v.z;
        spx[(b0+3)*LSTRIDE + ec] = v.w;
      }
      LGKM0;                                  // staging writes retired
      __builtin_amdgcn_s_barrier();           // RAW: spx visible to all waves
      #pragma unroll
      for (int e = 0; e < 128; e += 4) {
        float4 p4 = *(const float4*)&spx[lane*LSTRIDE + (e ^ sw4)];
        A0 = __fadd_rn(A0, __fmul_rn(p4.x, W0[ch*128 + e + 0]));
        A1 = __fadd_rn(A1, __fmul_rn(p4.x, W1[ch*128 + e + 0]));
        A0 = __fadd_rn(A0, __fmul_rn(p4.y, W0[ch*128 + e + 1]));
        A1 = __fadd_rn(A1, __fmul_rn(p4.y, W1[ch*128 + e + 1]));
        A0 = __fadd_rn(A0, __fmul_rn(p4.z, W0[ch*128 + e + 2]));
        A1 = __fadd_rn(A1, __fmul_rn(p4.z, W1[ch*128 + e + 2]));
        A0 = __fadd_rn(A0, __fmul_rn(p4.w, W0[ch*128 + e + 3]));
        A1 = __fadd_rn(A1, __fmul_rn(p4.w, W1[ch*128 + e + 3]));
      }
    }
    B0 = __fadd_rn(A0, biaA);
    B1 = __fadd_rn(A1, biaB);
  };

  compute_xw(0);   // prologue: xw for t=0

  #pragma unroll 1
  for (int t = 0; t < TT; ++t) {
    const float* hp = hfull + (size_t)t*(HH*BB);        // h(t-1), write-once slot
    float*       rn = hfull + (size_t)(t+1)*(HH*BB);    // h(t) destination

    // ---- h @ U: 1 raw barrier/chunk; vmcnt never drained in this loop ----
    load_chunk(hp, 0);
    float R0 = 0.f, R1 = 0.f, T0 = 0.f, T1 = 0.f;
    #pragma unroll 1
    for (int hc = 0; hc < 8; ++hc) {
      float* cur = (hc & 1) ? sB : sA;
      store_chunk(cur);                    // waits pre deps (counted vmcnt, not 0)
      if (hc < 7) load_chunk(hp, hc + 1);  // prefetch stays in flight across barrier
      LGKM0;                               // staging writes retired
      __builtin_amdgcn_s_barrier();        // (WAR on cur guaranteed by bar(hc-1))
      #pragma unroll
      for (int sub = 0; sub < 4; ++sub) {
        int kabs = hc*128 + sub*32;
        if (kabs == 288 || kabs == 576 || kabs == 864) {   // Eigen C += panel (CR add)
          T0 = __fadd_rn(T0, R0); R0 = 0.f;
          T1 = __fadd_rn(T1, R1); R1 = 0.f;
        }
        #pragma unroll
        for (int q = sub*32; q < sub*32 + 32; q += 4) {
          float4 h4 = *(const float4*)&cur[lane*LSTRIDE + (q ^ sw4)];
          R0 = __fadd_rn(R0, __fmul_rn(h4.x, U0[hc*128 + q + 0]));
          R1 = __fadd_rn(R1, __fmul_rn(h4.x, U1[hc*128 + q + 0]));
          R0 = __fadd_rn(R0, __fmul_rn(h4.y, U0[hc*128 + q + 1]));
          R1 = __fadd_rn(R1, __fmul_rn(h4.y, U1[hc*128 + q + 1]));
          R0 = __fadd_rn(R0, __fmul_rn(h4.z, U0[hc*128 + q + 2]));
          R1 = __fadd_rn(R1, __fmul_rn(h4.z, U1[hc*128 + q + 2]));
          R0 = __fadd_rn(R0, __fmul_rn(h4.w, U0[hc*128 + q + 3]));
          R1 = __fadd_rn(R1, __fmul_rn(h4.w, U1[hc*128 + q + 3]));
        }
      }
    }
    T0 = __fadd_rn(T0, R0);                 // final panel fold
    T1 = __fadd_rn(T1, R1);
    float z0 = __fadd_rn(B0, T0);           // z = fl(xw + hU)
    float z1 = __fadd_rn(B1, T1);

    // ---- gates: half1 computes tanh(zc), sig(zo); half0 computes sig(zi), sig(zf) ----
    float igv = 0.f, fgv = 0.f, hv = 0.f;
    if (half) {
      float th  = xla_tanh(z1);
      float ogs = xla_sigmoid(z0);
      xch[p*64 + lane]       = th;
      xch[256 + p*64 + lane] = ogs;
    } else {
      igv = xla_sigmoid(z0);
      fgv = xla_sigmoid(z1);
    }
    LGKM0;
    __builtin_amdgcn_s_barrier();           // xch visible (LDS-only hazard)
    if (!half) {
      float th  = xch[p*64 + lane];
      float ogs = xch[256 + p*64 + lane];
      c = __fadd_rn(__fmul_rn(fgv, c), __fmul_rn(igv, th));
      hv = __fmul_rn(ogs, xla_tanh(c));
      __hip_atomic_store(&rn[(size_t)ju*BB + lane], hv,
                         __ATOMIC_RELAXED, __HIP_MEMORY_SCOPE_AGENT);
    }
    __syncthreads();   // REQUIRED vmcnt(0) drain: all waves' h stores done before flag
    if (tid == 0)
      __hip_atomic_store(&flags[blockIdx.x], t+1, __ATOMIC_RELEASE, __HIP_MEMORY_SCOPE_AGENT);

    if (t < TT-1) {
      compute_xw(t+1);    // overlapped with other blocks finishing step t
      if (w == 0) {       // wave0 polls all 256 flags (4 per lane)
        for (;;) {
          int m0 = __hip_atomic_load(&flags[lane],       __ATOMIC_RELAXED, __HIP_MEMORY_SCOPE_AGENT);
          int m1 = __hip_atomic_load(&flags[64 + lane],  __ATOMIC_RELAXED, __HIP_MEMORY_SCOPE_AGENT);
          int m2 = __hip_atomic_load(&flags[128 + lane], __ATOMIC_RELAXED, __HIP_MEMORY_SCOPE_AGENT);
          int m3 = __hip_atomic_load(&flags[192 + lane], __ATOMIC_RELAXED, __HIP_MEMORY_SCOPE_AGENT);
          int mm = m0 < m1 ? m0 : m1;
          int nn = m2 < m3 ? m2 : m3;
          mm = mm < nn ? mm : nn;
          if (__all(mm >= t+1)) break;
          __builtin_amdgcn_s_sleep(1);
        }
        __atomic_signal_fence(__ATOMIC_ACQUIRE);
      }
      __syncthreads();
    }
  }
}

// ---------------- logits + gumbel argmax: XLA-CPU faithful (reads hfull slot t+1) -------
__global__ __launch_bounds__(256, 2) void logits_samp(
    const float* __restrict__ hfull, const float* __restrict__ Wo,
    const float* __restrict__ bo, const int* __restrict__ gnp,
    unsigned long long* __restrict__ best)
{
  const int t = 64 + blockIdx.y;
  if (t < gnp[0]) return;
  const int vt   = blockIdx.x;     // [0,8)
  const int z    = blockIdx.z;     // [0,4) b-quarter
  const int tid  = threadIdx.x;
  const int w    = tid >> 6;
  const int lane = tid & 63;

  int v[4], vc[4]; bool val[4];
  #pragma unroll
  for (int vj = 0; vj < 4; ++vj) {
    v[vj]  = vt*1024 + vj*256 + tid;
    val[vj] = (v[vj] < VV);
    vc[vj] = val[vj] ? v[vj] : (VV-1);
  }

  __shared__ float hds[128*16];
  __shared__ unsigned long long red[4][16];

  float tot[64], reg[64];
  #pragma unroll
  for (int i = 0; i < 64; ++i) { tot[i] = 0.f; reg[i] = 0.f; }

  const float* hf = hfull + (size_t)(t+1)*(HH*BB);   // h(t) lives in slot t+1

  #pragma unroll 1
  for (int kc8 = 0; kc8 < 8; ++kc8) {
    __syncthreads();
    #pragma unroll
    for (int s = 0; s < 8; ++s) {
      int idx = s*256 + tid;
      int kl = idx >> 4, bb = idx & 15;
      hds[idx] = hf[(size_t)(kc8*128 + kl)*BB + z*16 + bb];
    }
    __syncthreads();
    #pragma unroll 1
    for (int sub = 0; sub < 4; ++sub) {
      int kabs = kc8*128 + sub*32;
      if (kabs == 288 || kabs == 576 || kabs == 864) {
        #pragma unroll
        for (int i = 0; i < 64; ++i) { tot[i] = __fadd_rn(tot[i], reg[i]); reg[i] = 0.f; }
      }
      #pragma unroll 2
      for (int k = sub*32; k < sub*32 + 32; ++k) {
        const float* wr = Wo + (size_t)(kc8*128 + k)*VV;
        float wv0 = wr[vc[0]], wv1 = wr[vc[1]], wv2 = wr[vc[2]], wv3 = wr[vc[3]];
        #pragma unroll
        for (int bb = 0; bb < 16; ++bb) {
          float hb = hds[k*16 + bb];
          reg[0*16+bb] = __fadd_rn(reg[0*16+bb], __fmul_rn(hb, wv0));
          reg[1*16+bb] = __fadd_rn(reg[1*16+bb], __fmul_rn(hb, wv1));
          reg[2*16+bb] = __fadd_rn(reg[2*16+bb], __fmul_rn(hb, wv2));
          reg[3*16+bb] = __fadd_rn(reg[3*16+bb], __fmul_rn(hb, wv3));
        }
      }
    }
  }
  #pragma unroll
  for (int i = 0; i < 64; ++i) tot[i] = __fadd_rn(tot[i], reg[i]);

  uint32_t kt0, kt1;
  tf2x32(0u, 1u, 0u, (uint32_t)t, kt0, kt1);
  float bov[4];
  #pragma unroll
  for (int vj = 0; vj < 4; ++vj) bov[vj] = val[vj] ? bo[v[vj]] : 0.f;

  #pragma unroll 1
  for (int bb = 0; bb < 16; ++bb) {
    int bglob = z*16 + bb;
    unsigned long long pm = 0ull;
    #pragma unroll
    for (int vj = 0; vj < 4; ++vj) {
      if (val[vj]) {
        uint32_t y0, y1;
        tf2x32(kt0, kt1, 0u, (uint32_t)(bglob*VV + v[vj]), y0, y1);
        float u  = u01f(y0 ^ y1);
        float l1 = logf(u);
        float l2 = logf(-l1);
        float g  = -l2;
        float L  = __fadd_rn(tot[vj*16 + bb], bov[vj]);
        float sc = __fadd_rn(g, L);
        unsigned long long pk = pack32(sc, v[vj]);
        if (pk > pm) pm = pk;
      }
    }
    #pragma unroll
    for (int m = 32; m > 0; m >>= 1) {
      unsigned long long q = __shfl_xor(pm, m);
      if (q > pm) pm = q;
    }
    if (lane == 0) red[w][bb] = pm;
    __syncthreads();
    if (tid == 0) {
      unsigned long long m0 = red[0][bb];
      if (red[1][bb] > m0) m0 = red[1][bb];
      if (red[2][bb] > m0) m0 = red[2][bb];
      if (red[3][bb] > m0) m0 = red[3][bb];
      atomicMax(&best[(size_t)t*BB + z*16 + bb], m0);
    }
    __syncthreads();
  }
}

// ---------------- finalize ----------------
__global__ void finalize(const int* __restrict__ x, const int* __restrict__ gnp,
                         const unsigned long long* __restrict__ best, int* __restrict__ out)
{
  int i = blockIdx.x*256 + threadIdx.x;
  if (i >= BB*TT) return;
  int t = i & 127;
  int b = i >> 7;
  if (t < gnp[0] || t < 64) out[i] = x[i];
  else out[i] = 8191 - (int)(best[(size_t)t*BB + b] & 0x1FFFull);
}

// ---------------- launch ----------------
extern "C" void kernel_launch(void* const* d_in, const int* in_sizes, int n_in,
                              void* d_out, int out_size, void* d_ws, size_t ws_size,
                              hipStream_t stream)
{
  const int*   x    = (const int*)  d_in[0];
  const int*   gn   = (const int*)  d_in[1];
  const float* emb  = (const float*)d_in[2];
  const float* Wi   = (const float*)d_in[3];
  const float* Ui   = (const float*)d_in[4];
  const float* bi   = (const float*)d_in[5];
  const float* Wf   = (const float*)d_in[6];
  const float* Uf   = (const float*)d_in[7];
  const float* bf   = (const float*)d_in[8];
  const float* Wog  = (const float*)d_in[9];
  const float* Uog  = (const float*)d_in[10];
  const float* bog  = (const float*)d_in[11];
  const float* Wc   = (const float*)d_in[12];
  const float* Uc   = (const float*)d_in[13];
  const float* bc   = (const float*)d_in[14];
  const float* Wo   = (const float*)d_in[15];
  const float* bo   = (const float*)d_in[16];

  // ws: Ut 16MB | Wt 4MB | hfull 32.25MB (129 write-once h slots; doubles as hist)
  //     | px 8MB | best 64KB | flags 1KB   (~60.3MB total)
  float* Ut    = (float*)d_ws;                             // 4Mi floats
  float* Wt    = Ut + (size_t)4*1024*1024;                 // 1Mi floats
  float* hfull = Wt + (size_t)1024*1024;                   // 129*65536 floats
  float* px    = hfull + (size_t)(TT+1)*HH*BB;             // 128*256*64 floats
  unsigned long long* best =
      (unsigned long long*)(px + (size_t)TT*EE*BB);        // 8192 u64
  int* flags  = (int*)(best + (size_t)TT*BB);              // 256 int

  initz<<<512, 256, 0, stream>>>(hfull, best, flags);
  transpose4f<<<dim3(256,4), 256, 0, stream>>>(Ui, Uf, Uog, Uc, Ut, 1024, 1024);
  transpose4f<<<dim3(64,4),  256, 0, stream>>>(Wi, Wf, Wog, Wc, Wt, 256, 1024);
  pxgen<<<8192, 256, 0, stream>>>(x, emb, px);

  const float* Wtp = Wt; const float* Utp = Ut;
  const float* bip = bi; const float* bfp = bf; const float* bogp = bog; const float* bcp = bc;
  const float* pxp = px; float* hfullp = hfull; int* flagsp = flags;
  void* kargs[] = { (void*)&Wtp, (void*)&Utp,
                    (void*)&bip, (void*)&bfp, (void*)&bogp, (void*)&bcp,
                    (void*)&pxp, (void*)&hfullp, (void*)&flagsp };
  hipLaunchCooperativeKernel((void*)lstm_rec, dim3(256), dim3(512), kargs, 0, stream);

  logits_samp<<<dim3(8,64,4), 256, 0, stream>>>(hfull, Wo, bo, gn, best);
  finalize<<<32, 256, 0, stream>>>(x, gn, best, (int*)d_out);
}